// Round 3
// baseline (1206.884 us; speedup 1.0000x reference)
//
#include <hip/hip_runtime.h>
#include <hip/hip_bf16.h>
#include <math.h>

typedef __hip_bfloat16 bf16;

#define B_ 512
#define T_ 10
#define N_ 50
#define H_ 200
#define E_ 10000
#define R_ 200
#define K3 600   // 3*H

__device__ __forceinline__ float b2f(bf16 x){ return __bfloat162float(x); }

// ---------------------------------------------------------------- init
__global__ void k_init(float* lossacc){ if(threadIdx.x < 4) lossacc[threadIdx.x] = 0.f; }

// ---------------------------------------------------------------- entity projection: ep[side][e][g] = sum_h ent[e][h] * Wn_side[g][h]  (bf16 out)
__global__ __launch_bounds__(256) void k_entproj(
    const float* __restrict__ ent, const float* __restrict__ Wa0, const float* __restrict__ Wa1,
    bf16* __restrict__ ep)
{
  int side = blockIdx.y;
  const float* Wa = side ? Wa1 : Wa0;
  bf16* epo = ep + (size_t)side * E_ * H_;
  int e0 = blockIdx.x * 8;
  __shared__ float er[8][H_];
  int tid = threadIdx.x;
  for (int i = tid; i < 8 * H_ / 4; i += 256) {
    float4 v4 = *(const float4*)&ent[(size_t)e0 * H_ + i * 4];
    er[(i * 4) / H_][(i * 4) % H_ + 0] = v4.x;
    er[(i * 4) / H_][(i * 4) % H_ + 1] = v4.y;
    er[(i * 4) / H_][(i * 4) % H_ + 2] = v4.z;
    er[(i * 4) / H_][(i * 4) % H_ + 3] = v4.w;
  }
  __syncthreads();
  int g = tid;
  if (g < H_) {
    const float* wr = Wa + (size_t)g * K3;   // cols [0,H) = Wn
    float acc[8] = {};
    for (int k = 0; k < H_; k += 4) {
      float4 w4 = *(const float4*)&wr[k];
      #pragma unroll
      for (int ee = 0; ee < 8; ee++)
        acc[ee] += er[ee][k] * w4.x + er[ee][k+1] * w4.y + er[ee][k+2] * w4.z + er[ee][k+3] * w4.w;
    }
    #pragma unroll
    for (int ee = 0; ee < 8; ee++) epo[(size_t)(e0 + ee) * H_ + g] = __float2bfloat16(acc[ee]);
  }
}

// ---------------------------------------------------------------- attention bias: biasb[side][b][g] = ba[g] + se.Ws_row + re.Wr_row
__global__ __launch_bounds__(256) void k_bias(
    const float* __restrict__ ent, const int* __restrict__ trip,
    const float* __restrict__ Wa0, const float* __restrict__ Wa1,
    const float* __restrict__ ba0, const float* __restrict__ ba1,
    float* __restrict__ biasb)
{
  int b = blockIdx.x, side = blockIdx.y;
  const float* Wa = side ? Wa1 : Wa0;
  const float* ba = side ? ba1 : ba0;
  int ids = trip[b * 3 + (side ? 2 : 0)];
  int rid = trip[b * 3 + 1];
  __shared__ float se[H_], re[H_];
  int tid = threadIdx.x;
  if (tid < H_) {
    se[tid] = ent[(size_t)ids * H_ + tid];
    re[tid] = ent[(size_t)rid * H_ + tid];   // reference uses ent_embeds[rids]
  }
  __syncthreads();
  int g = tid;
  if (g < H_) {
    const float* row = Wa + (size_t)g * K3;
    float acc = ba[g];
    for (int h = 0; h < H_; h += 4) {
      float4 ws4 = *(const float4*)&row[H_ + h];
      float4 wr4 = *(const float4*)&row[2 * H_ + h];
      acc += se[h] * ws4.x + se[h+1] * ws4.y + se[h+2] * ws4.z + se[h+3] * ws4.w
           + re[h] * wr4.x + re[h+1] * wr4.y + re[h+2] * wr4.z + re[h+3] * wr4.w;
    }
    biasb[((size_t)side * B_ + b) * H_ + g] = acc;
  }
}

// ---------------------------------------------------------------- gibase[side][b][o] = bih[o] + se.Wih[o,H:2H] + rr.Wih[o,2H:3H]
__global__ __launch_bounds__(256) void k_gibase(
    const float* __restrict__ ent, const float* __restrict__ rel, const int* __restrict__ trip,
    const float* __restrict__ Wih0, const float* __restrict__ Wih1,
    const float* __restrict__ bih0, const float* __restrict__ bih1,
    float* __restrict__ gibase)
{
  int b = blockIdx.x, side = blockIdx.y;
  const float* Wih = side ? Wih1 : Wih0;
  const float* bih = side ? bih1 : bih0;
  int ids = trip[b * 3 + (side ? 2 : 0)];
  int rid = trip[b * 3 + 1];
  __shared__ float se[H_], rr[H_];
  int tid = threadIdx.x;
  if (tid < H_) {
    se[tid] = ent[(size_t)ids * H_ + tid];
    rr[tid] = rel[(size_t)rid * H_ + tid];
  }
  __syncthreads();
  for (int o = tid; o < K3; o += 256) {
    const float* wr = Wih + (size_t)o * K3;
    float acc = bih[o];
    for (int k = 0; k < H_; k += 4) {
      float4 w2 = *(const float4*)&wr[H_ + k];
      float4 w3 = *(const float4*)&wr[2 * H_ + k];
      acc += se[k] * w2.x + se[k+1] * w2.y + se[k+2] * w2.z + se[k+3] * w2.w
           + rr[k] * w3.x + rr[k+1] * w3.y + rr[k+2] * w3.z + rr[k+3] * w3.w;
    }
    gibase[((size_t)side * B_ + b) * K3 + o] = acc;
  }
}

// ---------------------------------------------------------------- attention -> step[side][b][t][h] (bf16, masked)
__global__ __launch_bounds__(256) void k_attn(
    const float* __restrict__ ent,
    const int* __restrict__ neigh0, const int* __restrict__ neigh1,
    const int* __restrict__ nlen0, const int* __restrict__ nlen1,
    const int* __restrict__ hlen0, const int* __restrict__ hlen1,
    const float* __restrict__ v0, const float* __restrict__ v1,
    const bf16* __restrict__ ep, const float* __restrict__ biasb,
    bf16* __restrict__ stepb)
{
  int side = blockIdx.y;
  int bt = blockIdx.x;
  int b = bt / T_, t = bt % T_;
  const int* neigh = side ? neigh1 : neigh0;
  const int* nlenA = side ? nlen1 : nlen0;
  const int* hlenA = side ? hlen1 : hlen0;
  const float* v = side ? v1 : v0;
  const bf16* epo = ep + (size_t)side * E_ * H_;
  const float* brow = biasb + ((size_t)side * B_ + b) * H_;

  __shared__ float bsh[H_], vsh[H_], lg[64], wsh[64];
  __shared__ int nb[N_];
  int tid = threadIdx.x;
  if (tid < H_) { bsh[tid] = brow[tid]; vsh[tid] = v[tid]; }
  if (tid < N_) nb[tid] = neigh[((size_t)b * T_ + t) * N_ + tid];
  int nl = nlenA[b * T_ + t];
  int hl = hlenA[b];
  __syncthreads();

  int wave = tid >> 6, lane = tid & 63;
  for (int n = wave; n < N_; n += 4) {
    float acc = 0.f;
    const bf16* er = epo + (size_t)nb[n] * H_;
    for (int g = lane; g < H_; g += 64) acc += tanhf(b2f(er[g]) + bsh[g]) * vsh[g];
    for (int off = 32; off > 0; off >>= 1) acc += __shfl_down(acc, off);
    if (lane == 0) lg[n] = (n < nl) ? acc : -1e30f;
  }
  __syncthreads();
  if (tid < 64) {
    float x = (tid < nl) ? lg[tid] : -1e30f;
    float m = x;
    for (int off = 32; off > 0; off >>= 1) m = fmaxf(m, __shfl_down(m, off));
    m = __shfl(m, 0);
    float e = (tid < nl) ? expf(x - m) : 0.f;
    float s = e;
    for (int off = 32; off > 0; off >>= 1) s += __shfl_down(s, off);
    s = __shfl(s, 0);
    if (tid < N_) wsh[tid] = e / s;
  }
  __syncthreads();
  int h = tid;
  if (h < H_) {
    float st = 0.f;
    for (int n = 0; n < nl; n++) st += wsh[n] * ent[(size_t)nb[n] * H_ + h];
    float msk = (t < hl) ? 1.f : 0.f;
    stepb[(((size_t)side * B_ + b) * T_ + t) * H_ + h] = __float2bfloat16(st * msk);
  }
}

// ---------------------------------------------------------------- GRU with fused input-GEMM. Block = 4 batch rows, all T steps.
__global__ __launch_bounds__(256) void k_gru(
    const bf16* __restrict__ stepb, const float* __restrict__ gibase,
    const float* __restrict__ Wih0, const float* __restrict__ Wih1,
    const float* __restrict__ Whh0, const float* __restrict__ Whh1,
    const float* __restrict__ bhh0, const float* __restrict__ bhh1,
    const int* __restrict__ len0, const int* __restrict__ len1,
    float* __restrict__ hfin)
{
  int side = blockIdx.y;
  const float* Wih = side ? Wih1 : Wih0;
  const float* Whh = side ? Whh1 : Whh0;
  const float* bhh = side ? bhh1 : bhh0;
  const int* len = side ? len1 : len0;
  const bf16* stp = stepb + (size_t)side * B_ * T_ * H_;
  const float* gib = gibase + (size_t)side * B_ * K3;
  float* hf = hfin + (size_t)side * B_ * H_;
  int b0 = blockIdx.x * 4;

  __shared__ float hsh[4][H_];
  __shared__ float ssh[4][H_];
  __shared__ float ghi[4][K3];
  __shared__ float ghh[4][K3];
  int tid = threadIdx.x;
  int l0 = len[b0], l1 = len[b0+1], l2 = len[b0+2], l3 = len[b0+3];
  int maxlen = max(max(l0,l1), max(l2,l3));
  for (int i = tid; i < 4 * H_; i += 256) hsh[i / H_][i % H_] = 0.f;
  __syncthreads();

  for (int t = 0; t < T_; t++) {
    if (t >= maxlen) break;   // uniform across block
    for (int i = tid; i < 4 * H_; i += 256) {
      int bb = i / H_, k = i % H_;
      ssh[bb][k] = b2f(stp[(((size_t)(b0 + bb)) * T_ + t) * H_ + k]);
    }
    __syncthreads();
    for (int o = tid; o < K3; o += 256) {
      const float* w1 = Wih + (size_t)o * K3;   // cols [0,H)
      const float* wh = Whh + (size_t)o * H_;
      float ai0=0, ai1=0, ai2=0, ai3=0, ah0=0, ah1=0, ah2=0, ah3=0;
      for (int k = 0; k < H_; k += 4) {
        float4 wi4 = *(const float4*)&w1[k];
        float4 wh4 = *(const float4*)&wh[k];
        #pragma unroll
        for (int j = 0; j < 4; j++) {
          float w_i = (j==0)?wi4.x:(j==1)?wi4.y:(j==2)?wi4.z:wi4.w;
          float w_h = (j==0)?wh4.x:(j==1)?wh4.y:(j==2)?wh4.z:wh4.w;
          ai0 += ssh[0][k+j] * w_i; ah0 += hsh[0][k+j] * w_h;
          ai1 += ssh[1][k+j] * w_i; ah1 += hsh[1][k+j] * w_h;
          ai2 += ssh[2][k+j] * w_i; ah2 += hsh[2][k+j] * w_h;
          ai3 += ssh[3][k+j] * w_i; ah3 += hsh[3][k+j] * w_h;
        }
      }
      float bb_ = bhh[o];
      ghi[0][o] = ai0 + gib[(size_t)(b0+0) * K3 + o];
      ghi[1][o] = ai1 + gib[(size_t)(b0+1) * K3 + o];
      ghi[2][o] = ai2 + gib[(size_t)(b0+2) * K3 + o];
      ghi[3][o] = ai3 + gib[(size_t)(b0+3) * K3 + o];
      ghh[0][o] = ah0 + bb_; ghh[1][o] = ah1 + bb_;
      ghh[2][o] = ah2 + bb_; ghh[3][o] = ah3 + bb_;
    }
    __syncthreads();
    for (int idx = tid; idx < 4 * H_; idx += 256) {
      int bb = idx / H_, j = idx % H_;
      float ir = ghi[bb][j], iz = ghi[bb][H_ + j], inn = ghi[bb][2 * H_ + j];
      float hr = ghh[bb][j], hz = ghh[bb][H_ + j], hn = ghh[bb][2 * H_ + j];
      float rg = 1.f / (1.f + expf(-(ir + hr)));
      float zg = 1.f / (1.f + expf(-(iz + hz)));
      float ng = tanhf(inn + rg * hn);
      float hp = hsh[bb][j];
      float hnew = (1.f - zg) * ng + zg * hp;
      int lb = (bb == 0) ? l0 : (bb == 1) ? l1 : (bb == 2) ? l2 : l3;
      hsh[bb][j] = (t < lb) ? hnew : hp;
    }
    __syncthreads();
  }
  for (int idx = tid; idx < 4 * H_; idx += 256) {
    int bb = idx / H_, j = idx % H_;
    hf[(size_t)(b0 + bb) * H_ + j] = hsh[bb][j];
  }
}

// ---------------------------------------------------------------- stable descending argsort of hist_len
__global__ __launch_bounds__(512) void k_argsort(
    const int* __restrict__ hlen0, const int* __restrict__ hlen1,
    int* __restrict__ idxbuf, float* __restrict__ dout)
{
  int side = blockIdx.x;                 // 0: s_idx, 1: o_idx
  const int* len = side ? hlen1 : hlen0;
  __shared__ int lens[B_];
  __shared__ int perm[B_];
  int tid = threadIdx.x;
  lens[tid] = len[tid];
  __syncthreads();
  int L = lens[tid];
  int rank = 0;
  for (int j = 0; j < B_; j++) {
    int Lj = lens[j];
    rank += (Lj > L) || (Lj == L && j < tid);
  }
  perm[rank] = tid;
  __syncthreads();
  idxbuf[side * B_ + tid] = perm[tid];
  // output order: (loss, sub_pred, ob_pred, o_idx, s_idx)
  size_t base = 1 + (size_t)2 * B_ * E_ + (side ? 0 : B_);
  dout[base + tid] = (float)perm[tid];
}

// ---------------------------------------------------------------- assemble pred-GEMM input rows (fp32)
__global__ __launch_bounds__(256) void k_feat(
    const float* __restrict__ ent, const float* __restrict__ rel, const int* __restrict__ trip,
    const int* __restrict__ idxbuf, const float* __restrict__ hfin,
    float* __restrict__ xfeat)
{
  int i = blockIdx.x, p = blockIdx.y;    // p=0: sub_pred (o-side), p=1: ob_pred (s-side)
  int bi = idxbuf[(p == 0 ? 1 : 0) * B_ + i];
  int ent_id = (p == 0) ? trip[bi * 3 + 2] : trip[bi * 3 + 0];
  int rid = trip[bi * 3 + 1];
  const float* hsrc = hfin + (size_t)(p == 0 ? 1 : 0) * B_ * H_;
  float* x = xfeat + ((size_t)p * B_ + i) * K3;
  int h = threadIdx.x;
  if (h < H_) {
    x[h]          = ent[(size_t)ent_id * H_ + h];
    x[H_ + h]     = hsrc[(size_t)bi * H_ + h];
    x[2 * H_ + h] = rel[(size_t)rid * H_ + h];
  }
}

// ---------------------------------------------------------------- pred GEMM: C[m][n] = sum_k A[m][k]*B[n][k] + bias[n], fp32
#define TM 64
#define TN 64
#define TK 16
__global__ __launch_bounds__(256) void k_gemm(
    const float* __restrict__ A0, const float* __restrict__ A1,
    const float* __restrict__ B0, const float* __restrict__ B1,
    const float* __restrict__ bias0, const float* __restrict__ bias1,
    float* __restrict__ C0, float* __restrict__ C1,
    int M, int N, int K)
{
  int side = blockIdx.z;
  const float* A = side ? A1 : A0;
  const float* Bm = side ? B1 : B0;
  const float* bias = side ? bias1 : bias0;
  float* C = side ? C1 : C0;

  __shared__ alignas(16) float As[TK][TM + 4];
  __shared__ alignas(16) float Bs[TK][TN + 4];
  int m0 = blockIdx.x * TM, n0 = blockIdx.y * TN;
  int tid = threadIdx.x;
  int tx = tid & 15, ty = tid >> 4;
  float acc[4][4] = {};
  int arow = tid >> 2;          // 0..63
  int acol = (tid & 3) * 4;     // 0,4,8,12

  for (int k0 = 0; k0 < K; k0 += TK) {
    bool full = (k0 + TK <= K);
    if (full) {
      float4 a4 = *(const float4*)&A[(size_t)(m0 + arow) * K + k0 + acol];
      As[acol + 0][arow] = a4.x; As[acol + 1][arow] = a4.y;
      As[acol + 2][arow] = a4.z; As[acol + 3][arow] = a4.w;
      int nrow = n0 + arow;
      if (nrow < N) {
        float4 b4 = *(const float4*)&Bm[(size_t)nrow * K + k0 + acol];
        Bs[acol + 0][arow] = b4.x; Bs[acol + 1][arow] = b4.y;
        Bs[acol + 2][arow] = b4.z; Bs[acol + 3][arow] = b4.w;
      } else {
        Bs[acol + 0][arow] = 0.f; Bs[acol + 1][arow] = 0.f;
        Bs[acol + 2][arow] = 0.f; Bs[acol + 3][arow] = 0.f;
      }
    } else {
      #pragma unroll
      for (int u = 0; u < 4; u++) {
        int k = k0 + acol + u;
        As[acol + u][arow] = (k < K) ? A[(size_t)(m0 + arow) * K + k] : 0.f;
      }
      int nrow = n0 + arow;
      #pragma unroll
      for (int u = 0; u < 4; u++) {
        int k = k0 + acol + u;
        Bs[acol + u][arow] = (k < K && nrow < N) ? Bm[(size_t)nrow * K + k] : 0.f;
      }
    }
    __syncthreads();
    #pragma unroll
    for (int k = 0; k < TK; k++) {
      float4 a4 = *(const float4*)&As[k][ty * 4];
      float4 b4 = *(const float4*)&Bs[k][tx * 4];
      float av[4] = {a4.x, a4.y, a4.z, a4.w};
      float bv[4] = {b4.x, b4.y, b4.z, b4.w};
      #pragma unroll
      for (int i = 0; i < 4; i++)
        #pragma unroll
        for (int j = 0; j < 4; j++)
          acc[i][j] += av[i] * bv[j];
    }
    __syncthreads();
  }
  #pragma unroll
  for (int i = 0; i < 4; i++) {
    int m = m0 + ty * 4 + i;
    #pragma unroll
    for (int j = 0; j < 4; j++) {
      int n = n0 + tx * 4 + j;
      if (n < N) C[(size_t)m * N + n] = acc[i][j] + bias[n];
    }
  }
}

// ---------------------------------------------------------------- CE loss from fp32 pred rows in d_out
__global__ __launch_bounds__(256) void k_loss(
    const float* __restrict__ dout, const int* __restrict__ trip,
    const int* __restrict__ idxbuf, float* __restrict__ lossacc)
{
  int i = blockIdx.x, p = blockIdx.y;
  const float* row = dout + 1 + (size_t)p * B_ * E_ + (size_t)i * E_;
  __shared__ float red[256];
  int tid = threadIdx.x;
  float m = -1e30f;
  for (int e = tid; e < E_; e += 256) m = fmaxf(m, row[e]);
  red[tid] = m; __syncthreads();
  for (int s = 128; s > 0; s >>= 1) { if (tid < s) red[tid] = fmaxf(red[tid], red[tid + s]); __syncthreads(); }
  m = red[0]; __syncthreads();
  float s = 0.f;
  for (int e = tid; e < E_; e += 256) s += expf(row[e] - m);
  red[tid] = s; __syncthreads();
  for (int st = 128; st > 0; st >>= 1) { if (tid < st) red[tid] += red[tid + st]; __syncthreads(); }
  if (tid == 0) {
    int bi = idxbuf[(p == 0 ? 1 : 0) * B_ + i];
    int label = (p == 0) ? trip[bi * 3 + 0] : trip[bi * 3 + 2];
    float lp = row[label] - m - logf(red[0]);
    atomicAdd(lossacc, -lp / (float)B_);
  }
}

__global__ void k_loss_write(const float* __restrict__ lossacc, float* __restrict__ dout){
  if (threadIdx.x == 0) dout[0] = lossacc[0];
}

// ----------------------------------------------------------------
extern "C" void kernel_launch(void* const* d_in, const int* in_sizes, int n_in,
                              void* d_out, int out_size, void* d_ws, size_t ws_size,
                              hipStream_t stream)
{
  const int* trip = (const int*)d_in[0];
  const int* s_ne = (const int*)d_in[1];
  const int* s_nl = (const int*)d_in[2];
  const int* s_hl = (const int*)d_in[3];
  const int* o_ne = (const int*)d_in[4];
  const int* o_nl = (const int*)d_in[5];
  const int* o_hl = (const int*)d_in[6];
  const float* ent = (const float*)d_in[7];
  const float* rel = (const float*)d_in[8];
  const float* aw_s = (const float*)d_in[9];
  const float* ab_s = (const float*)d_in[10];
  const float* v_s  = (const float*)d_in[11];
  const float* aw_o = (const float*)d_in[12];
  const float* ab_o = (const float*)d_in[13];
  const float* v_o  = (const float*)d_in[14];
  const float* sub_wih = (const float*)d_in[15];
  const float* sub_whh = (const float*)d_in[16];
  const float* sub_bih = (const float*)d_in[17];
  const float* sub_bhh = (const float*)d_in[18];
  const float* ob_wih  = (const float*)d_in[19];
  const float* ob_whh  = (const float*)d_in[20];
  const float* ob_bih  = (const float*)d_in[21];
  const float* ob_bhh  = (const float*)d_in[22];
  const float* lin_sub_w = (const float*)d_in[23];
  const float* lin_sub_b = (const float*)d_in[24];
  const float* lin_ob_w  = (const float*)d_in[25];
  const float* lin_ob_b  = (const float*)d_in[26];
  float* dout = (float*)d_out;

  // workspace carve — total ~18.7 MB
  char* w = (char*)d_ws;
  bf16* ep      = (bf16*)w;  w += (size_t)2 * E_ * H_ * 2;        // 8,000,000 B
  bf16* stepb   = (bf16*)w;  w += (size_t)2 * B_ * T_ * H_ * 2;   // 4,096,000 B
  float* biasb  = (float*)w; w += (size_t)2 * B_ * H_ * 4;        //   819,200 B
  float* gibase = (float*)w; w += (size_t)2 * B_ * K3 * 4;        // 2,457,600 B
  float* hfin   = (float*)w; w += (size_t)2 * B_ * H_ * 4;        //   819,200 B
  float* xfeat  = (float*)w; w += (size_t)2 * B_ * K3 * 4;        // 2,457,600 B
  float* lossacc= (float*)w; w += 256;
  int* idxbuf   = (int*)w;   w += 4096;

  k_init<<<1, 64, 0, stream>>>(lossacc);
  k_entproj<<<dim3(E_ / 8, 2), 256, 0, stream>>>(ent, aw_s, aw_o, ep);
  k_bias<<<dim3(B_, 2), 256, 0, stream>>>(ent, trip, aw_s, aw_o, ab_s, ab_o, biasb);
  k_gibase<<<dim3(B_, 2), 256, 0, stream>>>(ent, rel, trip, sub_wih, ob_wih,
                                            sub_bih, ob_bih, gibase);
  k_attn<<<dim3(B_ * T_, 2), 256, 0, stream>>>(ent, s_ne, o_ne, s_nl, o_nl,
                                               s_hl, o_hl, v_s, v_o, ep, biasb, stepb);
  k_gru<<<dim3(B_ / 4, 2), 256, 0, stream>>>(stepb, gibase, sub_wih, ob_wih,
                                             sub_whh, ob_whh, sub_bhh, ob_bhh,
                                             s_hl, o_hl, hfin);
  k_argsort<<<2, 512, 0, stream>>>(s_hl, o_hl, idxbuf, dout);
  k_feat<<<dim3(B_, 2), 256, 0, stream>>>(ent, rel, trip, idxbuf, hfin, xfeat);
  // pred GEMM (M=512, N=10000, K=600): z=0 -> sub_pred (o-side, lin_ob), z=1 -> ob_pred (s-side, lin_sub)
  k_gemm<<<dim3(B_ / TM, (E_ + TN - 1) / TN, 2), 256, 0, stream>>>(
      xfeat, xfeat + (size_t)B_ * K3,
      lin_ob_w, lin_sub_w, lin_ob_b, lin_sub_b,
      dout + 1, dout + 1 + (size_t)B_ * E_,
      B_, E_, K3);
  k_loss<<<dim3(B_, 2), 256, 0, stream>>>(dout, trip, idxbuf, lossacc);
  k_loss_write<<<1, 64, 0, stream>>>(lossacc, dout);
}

// Round 4
// 927.444 us; speedup vs baseline: 1.3013x; 1.3013x over previous
//
#include <hip/hip_runtime.h>
#include <hip/hip_bf16.h>
#include <math.h>

typedef __hip_bfloat16 bf16;
typedef __attribute__((ext_vector_type(8))) short short8;
typedef __attribute__((ext_vector_type(4))) float f32x4;

#define B_ 512
#define T_ 10
#define N_ 50
#define H_ 200
#define E_ 10000
#define R_ 200
#define K3 600   // 3*H

__device__ __forceinline__ float b2f(bf16 x){ return __bfloat162float(x); }
__device__ __forceinline__ float sigm(float x){ return 1.f / (1.f + expf(-x)); }

// ---------------------------------------------------------------- init
__global__ void k_init(float* lossacc){ if(threadIdx.x < 4) lossacc[threadIdx.x] = 0.f; }

// ---------------------------------------------------------------- entity projection: ep[side][e][g] = sum_h ent[e][h] * Wn_side[g][h]  (bf16 out)
__global__ __launch_bounds__(256) void k_entproj(
    const float* __restrict__ ent, const float* __restrict__ Wa0, const float* __restrict__ Wa1,
    bf16* __restrict__ ep)
{
  int side = blockIdx.y;
  const float* Wa = side ? Wa1 : Wa0;
  bf16* epo = ep + (size_t)side * E_ * H_;
  int e0 = blockIdx.x * 8;
  __shared__ float er[8][H_];
  int tid = threadIdx.x;
  for (int i = tid; i < 8 * H_ / 4; i += 256) {
    float4 v4 = *(const float4*)&ent[(size_t)e0 * H_ + i * 4];
    er[(i * 4) / H_][(i * 4) % H_ + 0] = v4.x;
    er[(i * 4) / H_][(i * 4) % H_ + 1] = v4.y;
    er[(i * 4) / H_][(i * 4) % H_ + 2] = v4.z;
    er[(i * 4) / H_][(i * 4) % H_ + 3] = v4.w;
  }
  __syncthreads();
  int g = tid;
  if (g < H_) {
    const float* wr = Wa + (size_t)g * K3;   // cols [0,H) = Wn
    float acc[8] = {};
    for (int k = 0; k < H_; k += 4) {
      float4 w4 = *(const float4*)&wr[k];
      #pragma unroll
      for (int ee = 0; ee < 8; ee++)
        acc[ee] += er[ee][k] * w4.x + er[ee][k+1] * w4.y + er[ee][k+2] * w4.z + er[ee][k+3] * w4.w;
    }
    #pragma unroll
    for (int ee = 0; ee < 8; ee++) epo[(size_t)(e0 + ee) * H_ + g] = __float2bfloat16(acc[ee]);
  }
}

// ---------------------------------------------------------------- attention bias: biasb[side][b][g] = ba[g] + se.Ws_row + re.Wr_row
__global__ __launch_bounds__(256) void k_bias(
    const float* __restrict__ ent, const int* __restrict__ trip,
    const float* __restrict__ Wa0, const float* __restrict__ Wa1,
    const float* __restrict__ ba0, const float* __restrict__ ba1,
    float* __restrict__ biasb)
{
  int b = blockIdx.x, side = blockIdx.y;
  const float* Wa = side ? Wa1 : Wa0;
  const float* ba = side ? ba1 : ba0;
  int ids = trip[b * 3 + (side ? 2 : 0)];
  int rid = trip[b * 3 + 1];
  __shared__ float se[H_], re[H_];
  int tid = threadIdx.x;
  if (tid < H_) {
    se[tid] = ent[(size_t)ids * H_ + tid];
    re[tid] = ent[(size_t)rid * H_ + tid];   // reference uses ent_embeds[rids]
  }
  __syncthreads();
  int g = tid;
  if (g < H_) {
    const float* row = Wa + (size_t)g * K3;
    float acc = ba[g];
    for (int h = 0; h < H_; h += 4) {
      float4 ws4 = *(const float4*)&row[H_ + h];
      float4 wr4 = *(const float4*)&row[2 * H_ + h];
      acc += se[h] * ws4.x + se[h+1] * ws4.y + se[h+2] * ws4.z + se[h+3] * ws4.w
           + re[h] * wr4.x + re[h+1] * wr4.y + re[h+2] * wr4.z + re[h+3] * wr4.w;
    }
    biasb[((size_t)side * B_ + b) * H_ + g] = acc;
  }
}

// ---------------------------------------------------------------- gibase[side][b][o] = bih[o] + se.Wih[o,H:2H] + rr.Wih[o,2H:3H]  (bf16 out)
__global__ __launch_bounds__(256) void k_gibase(
    const float* __restrict__ ent, const float* __restrict__ rel, const int* __restrict__ trip,
    const float* __restrict__ Wih0, const float* __restrict__ Wih1,
    const float* __restrict__ bih0, const float* __restrict__ bih1,
    bf16* __restrict__ gibase)
{
  int b = blockIdx.x, side = blockIdx.y;
  const float* Wih = side ? Wih1 : Wih0;
  const float* bih = side ? bih1 : bih0;
  int ids = trip[b * 3 + (side ? 2 : 0)];
  int rid = trip[b * 3 + 1];
  __shared__ float se[H_], rr[H_];
  int tid = threadIdx.x;
  if (tid < H_) {
    se[tid] = ent[(size_t)ids * H_ + tid];
    rr[tid] = rel[(size_t)rid * H_ + tid];
  }
  __syncthreads();
  for (int o = tid; o < K3; o += 256) {
    const float* wr = Wih + (size_t)o * K3;
    float acc = bih[o];
    for (int k = 0; k < H_; k += 4) {
      float4 w2 = *(const float4*)&wr[H_ + k];
      float4 w3 = *(const float4*)&wr[2 * H_ + k];
      acc += se[k] * w2.x + se[k+1] * w2.y + se[k+2] * w2.z + se[k+3] * w2.w
           + rr[k] * w3.x + rr[k+1] * w3.y + rr[k+2] * w3.z + rr[k+3] * w3.w;
    }
    gibase[((size_t)side * B_ + b) * K3 + o] = __float2bfloat16(acc);
  }
}

// ---------------------------------------------------------------- pack GRU weights: Wc[side][n=608][k=448] bf16
// k<200: Wih[n][k] (step part); 224<=k<424: Whh[n][k-224]; else 0. rows>=600: 0.
__global__ __launch_bounds__(256) void k_wc(
    const float* __restrict__ Wih0, const float* __restrict__ Wih1,
    const float* __restrict__ Whh0, const float* __restrict__ Whh1,
    bf16* __restrict__ Wc)
{
  int n = blockIdx.x, side = blockIdx.y;
  const float* Wih = side ? Wih1 : Wih0;
  const float* Whh = side ? Whh1 : Whh0;
  bf16* out = Wc + ((size_t)side * 608 + n) * 448;
  for (int k = threadIdx.x; k < 448; k += 256) {
    float v = 0.f;
    if (n < 600) {
      if (k < 200) v = Wih[(size_t)n * K3 + k];
      else if (k >= 224 && k < 424) v = Whh[(size_t)n * H_ + (k - 224)];
    }
    out[k] = __float2bfloat16(v);
  }
}

// ---------------------------------------------------------------- attention -> step[side][b][t][h] (bf16, masked)
__global__ __launch_bounds__(256) void k_attn(
    const float* __restrict__ ent,
    const int* __restrict__ neigh0, const int* __restrict__ neigh1,
    const int* __restrict__ nlen0, const int* __restrict__ nlen1,
    const int* __restrict__ hlen0, const int* __restrict__ hlen1,
    const float* __restrict__ v0, const float* __restrict__ v1,
    const bf16* __restrict__ ep, const float* __restrict__ biasb,
    bf16* __restrict__ stepb)
{
  int side = blockIdx.y;
  int bt = blockIdx.x;
  int b = bt / T_, t = bt % T_;
  const int* neigh = side ? neigh1 : neigh0;
  const int* nlenA = side ? nlen1 : nlen0;
  const int* hlenA = side ? hlen1 : hlen0;
  const float* v = side ? v1 : v0;
  const bf16* epo = ep + (size_t)side * E_ * H_;
  const float* brow = biasb + ((size_t)side * B_ + b) * H_;

  __shared__ float bsh[H_], vsh[H_], lg[64], wsh[64];
  __shared__ int nb[N_];
  int tid = threadIdx.x;
  if (tid < H_) { bsh[tid] = brow[tid]; vsh[tid] = v[tid]; }
  if (tid < N_) nb[tid] = neigh[((size_t)b * T_ + t) * N_ + tid];
  int nl = nlenA[b * T_ + t];
  int hl = hlenA[b];
  __syncthreads();

  int wave = tid >> 6, lane = tid & 63;
  for (int n = wave; n < N_; n += 4) {
    float acc = 0.f;
    const bf16* er = epo + (size_t)nb[n] * H_;
    for (int g = lane; g < H_; g += 64) acc += tanhf(b2f(er[g]) + bsh[g]) * vsh[g];
    for (int off = 32; off > 0; off >>= 1) acc += __shfl_down(acc, off);
    if (lane == 0) lg[n] = (n < nl) ? acc : -1e30f;
  }
  __syncthreads();
  if (tid < 64) {
    float x = (tid < nl) ? lg[tid] : -1e30f;
    float m = x;
    for (int off = 32; off > 0; off >>= 1) m = fmaxf(m, __shfl_down(m, off));
    m = __shfl(m, 0);
    float e = (tid < nl) ? expf(x - m) : 0.f;
    float s = e;
    for (int off = 32; off > 0; off >>= 1) s += __shfl_down(s, off);
    s = __shfl(s, 0);
    if (tid < N_) wsh[tid] = e / s;
  }
  __syncthreads();
  int h = tid;
  if (h < H_) {
    float st = 0.f;
    for (int n = 0; n < nl; n++) st += wsh[n] * ent[(size_t)nb[n] * H_ + h];
    float msk = (t < hl) ? 1.f : 0.f;
    stepb[(((size_t)side * B_ + b) * T_ + t) * H_ + h] = __float2bfloat16(st * msk);
  }
}

// ---------------------------------------------------------------- MFMA GRU
// Block: 32 batch rows, both gate GEMMs per step via mfma_f32_16x16x32_bf16.
// A-panel Ax[32][456] bf16 in LDS: cols [0,200) = s_t, [224,424) = h, rest 0.
// Wc rows: [0,200)=r, [200,400)=z, [400,600)=n gates.
__global__ __launch_bounds__(256) void k_gru2(
    const bf16* __restrict__ stepb, const bf16* __restrict__ gibase,
    const bf16* __restrict__ Wc,
    const float* __restrict__ bhh0, const float* __restrict__ bhh1,
    const int* __restrict__ len0, const int* __restrict__ len1,
    float* __restrict__ hfin)
{
  int side = blockIdx.y;
  int b0 = blockIdx.x * 32;
  const bf16* stp = stepb + (size_t)side * B_ * T_ * H_;
  const bf16* gib = gibase + ((size_t)side * B_ + b0) * K3;
  const bf16* Wcs = Wc + (size_t)side * 608 * 448;
  const float* bhh = side ? bhh1 : bhh0;
  const int* len = side ? len1 : len0;

  __shared__ bf16 Ax[32][456];   // pad 448->456: row stride 912B = 228 dw -> 2-way banks (free)
  __shared__ bf16 H2[32][200];
  __shared__ int lens[32];

  int tid = threadIdx.x;
  int wave = tid >> 6, lane = tid & 63;
  int quad = lane >> 4, l15 = lane & 15;

  // zero A panel
  for (int i = tid; i < 32 * 456 / 8; i += 256) ((short8*)&Ax[0][0])[i] = (short8)0;
  if (tid < 32) lens[tid] = len[b0 + tid];
  __syncthreads();
  // load s_0
  for (int i = tid; i < 32 * 25; i += 256) {
    int row = i / 25, seg = i % 25;
    *(short8*)&Ax[row][seg * 8] =
        *(const short8*)&stp[(((size_t)(b0 + row)) * T_ + 0) * H_ + seg * 8];
  }
  __syncthreads();

  for (int t = 0; t < T_; t++) {
    for (int c = wave; c < 13; c += 4) {
      int j0 = c * 16;
      f32x4 ar0 = {0,0,0,0}, ar1 = {0,0,0,0};
      f32x4 az0 = {0,0,0,0}, az1 = {0,0,0,0};
      f32x4 ani0 = {0,0,0,0}, ani1 = {0,0,0,0};
      f32x4 anh0 = {0,0,0,0}, anh1 = {0,0,0,0};
      int nr = j0 + l15;
      const bf16* wr = Wcs + (size_t)nr * 448;
      const bf16* wz = Wcs + (size_t)(200 + nr) * 448;
      const bf16* wn = Wcs + (size_t)(400 + nr) * 448;
      #pragma unroll
      for (int ks = 0; ks < 14; ks++) {
        int kk = ks * 32 + quad * 8;
        short8 a0 = *(const short8*)&Ax[l15][kk];
        short8 a1 = *(const short8*)&Ax[16 + l15][kk];
        short8 br = *(const short8*)&wr[kk];
        short8 bz = *(const short8*)&wz[kk];
        short8 bn = *(const short8*)&wn[kk];
        ar0 = __builtin_amdgcn_mfma_f32_16x16x32_bf16(a0, br, ar0, 0, 0, 0);
        ar1 = __builtin_amdgcn_mfma_f32_16x16x32_bf16(a1, br, ar1, 0, 0, 0);
        az0 = __builtin_amdgcn_mfma_f32_16x16x32_bf16(a0, bz, az0, 0, 0, 0);
        az1 = __builtin_amdgcn_mfma_f32_16x16x32_bf16(a1, bz, az1, 0, 0, 0);
        if (ks < 7) {
          ani0 = __builtin_amdgcn_mfma_f32_16x16x32_bf16(a0, bn, ani0, 0, 0, 0);
          ani1 = __builtin_amdgcn_mfma_f32_16x16x32_bf16(a1, bn, ani1, 0, 0, 0);
        } else {
          anh0 = __builtin_amdgcn_mfma_f32_16x16x32_bf16(a0, bn, anh0, 0, 0, 0);
          anh1 = __builtin_amdgcn_mfma_f32_16x16x32_bf16(a1, bn, anh1, 0, 0, 0);
        }
      }
      // elementwise (all six gate values for (row, j) live in this lane)
      int j = j0 + l15;
      if (j < 200) {
        float bhr = bhh[j], bhz = bhh[200 + j], bhn = bhh[400 + j];
        #pragma unroll
        for (int mt = 0; mt < 2; mt++) {
          #pragma unroll
          for (int r = 0; r < 4; r++) {
            int row = mt * 16 + quad * 4 + r;
            const bf16* g = gib + (size_t)row * K3;
            float accr = mt ? ar1[r] : ar0[r];
            float accz = mt ? az1[r] : az0[r];
            float accni = mt ? ani1[r] : ani0[r];
            float accnh = mt ? anh1[r] : anh0[r];
            float rz = accr + b2f(g[j]) + bhr;          // ir + hr
            float zz = accz + b2f(g[200 + j]) + bhz;    // iz + hz
            float inn = accni + b2f(g[400 + j]);
            float hn  = accnh + bhn;
            float rg = sigm(rz);
            float zg = sigm(zz);
            float ng = tanhf(inn + rg * hn);
            float hold = b2f(Ax[row][224 + j]);
            float hnew = (1.f - zg) * ng + zg * hold;
            H2[row][j] = __float2bfloat16((t < lens[row]) ? hnew : hold);
          }
        }
      }
    }
    __syncthreads();
    // commit h, load next s
    for (int i = tid; i < 32 * 25; i += 256) {
      int row = i / 25, seg = i % 25;
      *(short8*)&Ax[row][224 + seg * 8] = *(const short8*)&H2[row][seg * 8];
    }
    if (t < T_ - 1) {
      for (int i = tid; i < 32 * 25; i += 256) {
        int row = i / 25, seg = i % 25;
        *(short8*)&Ax[row][seg * 8] =
            *(const short8*)&stp[(((size_t)(b0 + row)) * T_ + (t + 1)) * H_ + seg * 8];
      }
    }
    __syncthreads();
  }
  for (int i = tid; i < 32 * H_; i += 256) {
    int row = i / H_, j = i % H_;
    hfin[((size_t)side * B_ + b0 + row) * H_ + j] = b2f(Ax[row][224 + j]);
  }
}

// ---------------------------------------------------------------- stable descending argsort of hist_len
__global__ __launch_bounds__(512) void k_argsort(
    const int* __restrict__ hlen0, const int* __restrict__ hlen1,
    int* __restrict__ idxbuf, float* __restrict__ dout)
{
  int side = blockIdx.x;                 // 0: s_idx, 1: o_idx
  const int* len = side ? hlen1 : hlen0;
  __shared__ int lens[B_];
  __shared__ int perm[B_];
  int tid = threadIdx.x;
  lens[tid] = len[tid];
  __syncthreads();
  int L = lens[tid];
  int rank = 0;
  for (int j = 0; j < B_; j++) {
    int Lj = lens[j];
    rank += (Lj > L) || (Lj == L && j < tid);
  }
  perm[rank] = tid;
  __syncthreads();
  idxbuf[side * B_ + tid] = perm[tid];
  // output order: (loss, sub_pred, ob_pred, o_idx, s_idx)
  size_t base = 1 + (size_t)2 * B_ * E_ + (side ? 0 : B_);
  dout[base + tid] = (float)perm[tid];
}

// ---------------------------------------------------------------- assemble pred-GEMM input rows (bf16, K padded to 640)
__global__ __launch_bounds__(256) void k_feat(
    const float* __restrict__ ent, const float* __restrict__ rel, const int* __restrict__ trip,
    const int* __restrict__ idxbuf, const float* __restrict__ hfin,
    bf16* __restrict__ xfeat)
{
  int i = blockIdx.x, p = blockIdx.y;    // p=0: sub_pred (o-side), p=1: ob_pred (s-side)
  int bi = idxbuf[(p == 0 ? 1 : 0) * B_ + i];
  int ent_id = (p == 0) ? trip[bi * 3 + 2] : trip[bi * 3 + 0];
  int rid = trip[bi * 3 + 1];
  const float* hsrc = hfin + (size_t)(p == 0 ? 1 : 0) * B_ * H_;
  bf16* x = xfeat + ((size_t)p * B_ + i) * 640;
  int h = threadIdx.x;
  if (h < H_) {
    x[h]          = __float2bfloat16(ent[(size_t)ent_id * H_ + h]);
    x[H_ + h]     = __float2bfloat16(hsrc[(size_t)bi * H_ + h]);
    x[2 * H_ + h] = __float2bfloat16(rel[(size_t)rid * H_ + h]);
  }
  if (h < 40) x[600 + h] = __float2bfloat16(0.f);
}

// ---------------------------------------------------------------- MFMA pred GEMM: C[m][n] = sum_k A[m][k]*B[n][k] + bias[n]
// A bf16 [1024][640] (rows 0..512 side0, 512..1024 side1), B fp32 [10000][600] converted in staging.
// Tile M=128, N=64, BK=64.
__global__ __launch_bounds__(256) void k_gemm2(
    const bf16* __restrict__ Abf,
    const float* __restrict__ B0, const float* __restrict__ B1,
    const float* __restrict__ bias0, const float* __restrict__ bias1,
    float* __restrict__ dout)
{
  int side = blockIdx.z;
  const float* Bm = side ? B1 : B0;
  const float* bias = side ? bias1 : bias0;
  float* C = dout + 1 + (size_t)side * B_ * E_;
  int mBase = blockIdx.x * 128;             // row within side (0..511)
  int m0 = side * B_ + mBase;               // row in Abf
  int n0 = blockIdx.y * 64;

  __shared__ bf16 As[128][72];   // stride 144B = 36 dw -> 2-way banks
  __shared__ bf16 Bs[64][72];

  int tid = threadIdx.x;
  int wave = tid >> 6, lane = tid & 63;
  int quad = lane >> 4, l15 = lane & 15;

  f32x4 acc[8];
  #pragma unroll
  for (int mt = 0; mt < 8; mt++) acc[mt] = (f32x4){0,0,0,0};

  for (int k0 = 0; k0 < 640; k0 += 64) {
    // stage A: 128x64 bf16
    {
      int row = tid >> 1, c0 = (tid & 1) * 32;
      const bf16* src = Abf + (size_t)(m0 + row) * 640 + k0 + c0;
      #pragma unroll
      for (int u = 0; u < 4; u++)
        *(short8*)&As[row][c0 + u * 8] = *(const short8*)&src[u * 8];
    }
    // stage B: 64x64 fp32 -> bf16
    {
      int row = tid >> 2, c0 = (tid & 3) * 16;
      int n = n0 + row;
      if (n < E_ && k0 + c0 + 16 <= K3) {
        const float* src = Bm + (size_t)n * K3 + k0 + c0;
        #pragma unroll
        for (int u = 0; u < 16; u += 4) {
          float4 v = *(const float4*)&src[u];
          Bs[row][c0 + u + 0] = __float2bfloat16(v.x);
          Bs[row][c0 + u + 1] = __float2bfloat16(v.y);
          Bs[row][c0 + u + 2] = __float2bfloat16(v.z);
          Bs[row][c0 + u + 3] = __float2bfloat16(v.w);
        }
      } else {
        #pragma unroll
        for (int u = 0; u < 16; u++) {
          int k = k0 + c0 + u;
          float v = (n < E_ && k < K3) ? Bm[(size_t)n * K3 + k] : 0.f;
          Bs[row][c0 + u] = __float2bfloat16(v);
        }
      }
    }
    __syncthreads();
    #pragma unroll
    for (int ks = 0; ks < 2; ks++) {
      int kk = ks * 32 + quad * 8;
      short8 bfr = *(const short8*)&Bs[wave * 16 + l15][kk];
      #pragma unroll
      for (int mt = 0; mt < 8; mt++) {
        short8 afr = *(const short8*)&As[mt * 16 + l15][kk];
        acc[mt] = __builtin_amdgcn_mfma_f32_16x16x32_bf16(afr, bfr, acc[mt], 0, 0, 0);
      }
    }
    __syncthreads();
  }

  int n = n0 + wave * 16 + l15;
  if (n < E_) {
    float bv = bias[n];
    #pragma unroll
    for (int mt = 0; mt < 8; mt++) {
      #pragma unroll
      for (int r = 0; r < 4; r++) {
        int mrow = mBase + mt * 16 + quad * 4 + r;   // 0..511
        C[(size_t)mrow * E_ + n] = acc[mt][r] + bv;
      }
    }
  }
}

// ---------------------------------------------------------------- CE loss from fp32 pred rows in d_out
__global__ __launch_bounds__(256) void k_loss(
    const float* __restrict__ dout, const int* __restrict__ trip,
    const int* __restrict__ idxbuf, float* __restrict__ lossacc)
{
  int i = blockIdx.x, p = blockIdx.y;
  const float* row = dout + 1 + (size_t)p * B_ * E_ + (size_t)i * E_;
  __shared__ float red[256];
  int tid = threadIdx.x;
  float m = -1e30f;
  for (int e = tid; e < E_; e += 256) m = fmaxf(m, row[e]);
  red[tid] = m; __syncthreads();
  for (int s = 128; s > 0; s >>= 1) { if (tid < s) red[tid] = fmaxf(red[tid], red[tid + s]); __syncthreads(); }
  m = red[0]; __syncthreads();
  float s = 0.f;
  for (int e = tid; e < E_; e += 256) s += expf(row[e] - m);
  red[tid] = s; __syncthreads();
  for (int st = 128; st > 0; st >>= 1) { if (tid < st) red[tid] += red[tid + st]; __syncthreads(); }
  if (tid == 0) {
    int bi = idxbuf[(p == 0 ? 1 : 0) * B_ + i];
    int label = (p == 0) ? trip[bi * 3 + 0] : trip[bi * 3 + 2];
    float lp = row[label] - m - logf(red[0]);
    atomicAdd(lossacc, -lp / (float)B_);
  }
}

__global__ void k_loss_write(const float* __restrict__ lossacc, float* __restrict__ dout){
  if (threadIdx.x == 0) dout[0] = lossacc[0];
}

// ----------------------------------------------------------------
extern "C" void kernel_launch(void* const* d_in, const int* in_sizes, int n_in,
                              void* d_out, int out_size, void* d_ws, size_t ws_size,
                              hipStream_t stream)
{
  const int* trip = (const int*)d_in[0];
  const int* s_ne = (const int*)d_in[1];
  const int* s_nl = (const int*)d_in[2];
  const int* s_hl = (const int*)d_in[3];
  const int* o_ne = (const int*)d_in[4];
  const int* o_nl = (const int*)d_in[5];
  const int* o_hl = (const int*)d_in[6];
  const float* ent = (const float*)d_in[7];
  const float* rel = (const float*)d_in[8];
  const float* aw_s = (const float*)d_in[9];
  const float* ab_s = (const float*)d_in[10];
  const float* v_s  = (const float*)d_in[11];
  const float* aw_o = (const float*)d_in[12];
  const float* ab_o = (const float*)d_in[13];
  const float* v_o  = (const float*)d_in[14];
  const float* sub_wih = (const float*)d_in[15];
  const float* sub_whh = (const float*)d_in[16];
  const float* sub_bih = (const float*)d_in[17];
  const float* sub_bhh = (const float*)d_in[18];
  const float* ob_wih  = (const float*)d_in[19];
  const float* ob_whh  = (const float*)d_in[20];
  const float* ob_bih  = (const float*)d_in[21];
  const float* ob_bhh  = (const float*)d_in[22];
  const float* lin_sub_w = (const float*)d_in[23];
  const float* lin_sub_b = (const float*)d_in[24];
  const float* lin_ob_w  = (const float*)d_in[25];
  const float* lin_ob_b  = (const float*)d_in[26];
  float* dout = (float*)d_out;

  // workspace carve — total ~17.4 MB
  char* w = (char*)d_ws;
  bf16* ep      = (bf16*)w;  w += (size_t)2 * E_ * H_ * 2;        // 8,000,000 B
  bf16* stepb   = (bf16*)w;  w += (size_t)2 * B_ * T_ * H_ * 2;   // 4,096,000 B
  float* biasb  = (float*)w; w += (size_t)2 * B_ * H_ * 4;        //   819,200 B
  bf16* gibase  = (bf16*)w;  w += (size_t)2 * B_ * K3 * 2;        // 1,228,800 B
  float* hfin   = (float*)w; w += (size_t)2 * B_ * H_ * 4;        //   819,200 B
  bf16* xfeat   = (bf16*)w;  w += (size_t)1024 * 640 * 2;         // 1,310,720 B
  bf16* Wc      = (bf16*)w;  w += (size_t)2 * 608 * 448 * 2;      // 1,089,536 B
  float* lossacc= (float*)w; w += 256;
  int* idxbuf   = (int*)w;   w += 4096;

  k_init<<<1, 64, 0, stream>>>(lossacc);
  k_entproj<<<dim3(E_ / 8, 2), 256, 0, stream>>>(ent, aw_s, aw_o, ep);
  k_bias<<<dim3(B_, 2), 256, 0, stream>>>(ent, trip, aw_s, aw_o, ab_s, ab_o, biasb);
  k_gibase<<<dim3(B_, 2), 256, 0, stream>>>(ent, rel, trip, sub_wih, ob_wih,
                                            sub_bih, ob_bih, gibase);
  k_wc<<<dim3(608, 2), 256, 0, stream>>>(sub_wih, ob_wih, sub_whh, ob_whh, Wc);
  k_attn<<<dim3(B_ * T_, 2), 256, 0, stream>>>(ent, s_ne, o_ne, s_nl, o_nl,
                                               s_hl, o_hl, v_s, v_o, ep, biasb, stepb);
  k_gru2<<<dim3(B_ / 32, 2), 256, 0, stream>>>(stepb, gibase, Wc, sub_bhh, ob_bhh,
                                               s_hl, o_hl, hfin);
  k_argsort<<<2, 512, 0, stream>>>(s_hl, o_hl, idxbuf, dout);
  k_feat<<<dim3(B_, 2), 256, 0, stream>>>(ent, rel, trip, idxbuf, hfin, xfeat);
  // pred GEMM: z=0 -> sub_pred (o-side feats, lin_ob), z=1 -> ob_pred (s-side feats, lin_sub)
  k_gemm2<<<dim3(4, (E_ + 63) / 64, 2), 256, 0, stream>>>(
      xfeat, lin_ob_w, lin_sub_w, lin_ob_b, lin_sub_b, dout);
  k_loss<<<dim3(B_, 2), 256, 0, stream>>>(dout, trip, idxbuf, lossacc);
  k_loss_write<<<1, 64, 0, stream>>>(lossacc, dout);
}

// Round 5
// 788.385 us; speedup vs baseline: 1.5308x; 1.1764x over previous
//
#include <hip/hip_runtime.h>
#include <hip/hip_bf16.h>
#include <math.h>

typedef __hip_bfloat16 bf16;
typedef __attribute__((ext_vector_type(8))) short short8;
typedef __attribute__((ext_vector_type(4))) float f32x4;

#define B_ 512
#define T_ 10
#define N_ 50
#define H_ 200
#define E_ 10000
#define R_ 200
#define K3 600   // 3*H

__device__ __forceinline__ float b2f(bf16 x){ return __bfloat162float(x); }
__device__ __forceinline__ float sigm(float x){ return 1.f / (1.f + expf(-x)); }

// ---------------------------------------------------------------- init
__global__ void k_init(float* lossacc){ if(threadIdx.x < 4) lossacc[threadIdx.x] = 0.f; }

// ---------------------------------------------------------------- entity projection: ep[side][e][g] = sum_h ent[e][h] * Wn_side[g][h]  (bf16 out)
__global__ __launch_bounds__(256) void k_entproj(
    const float* __restrict__ ent, const float* __restrict__ Wa0, const float* __restrict__ Wa1,
    bf16* __restrict__ ep)
{
  int side = blockIdx.y;
  const float* Wa = side ? Wa1 : Wa0;
  bf16* epo = ep + (size_t)side * E_ * H_;
  int e0 = blockIdx.x * 8;
  __shared__ float er[8][H_];
  int tid = threadIdx.x;
  for (int i = tid; i < 8 * H_ / 4; i += 256) {
    float4 v4 = *(const float4*)&ent[(size_t)e0 * H_ + i * 4];
    er[(i * 4) / H_][(i * 4) % H_ + 0] = v4.x;
    er[(i * 4) / H_][(i * 4) % H_ + 1] = v4.y;
    er[(i * 4) / H_][(i * 4) % H_ + 2] = v4.z;
    er[(i * 4) / H_][(i * 4) % H_ + 3] = v4.w;
  }
  __syncthreads();
  int g = tid;
  if (g < H_) {
    const float* wr = Wa + (size_t)g * K3;   // cols [0,H) = Wn
    float acc[8] = {};
    for (int k = 0; k < H_; k += 4) {
      float4 w4 = *(const float4*)&wr[k];
      #pragma unroll
      for (int ee = 0; ee < 8; ee++)
        acc[ee] += er[ee][k] * w4.x + er[ee][k+1] * w4.y + er[ee][k+2] * w4.z + er[ee][k+3] * w4.w;
    }
    #pragma unroll
    for (int ee = 0; ee < 8; ee++) epo[(size_t)(e0 + ee) * H_ + g] = __float2bfloat16(acc[ee]);
  }
}

// ---------------------------------------------------------------- attention bias: biasb[side][b][g] = ba[g] + se.Ws_row + re.Wr_row
__global__ __launch_bounds__(256) void k_bias(
    const float* __restrict__ ent, const int* __restrict__ trip,
    const float* __restrict__ Wa0, const float* __restrict__ Wa1,
    const float* __restrict__ ba0, const float* __restrict__ ba1,
    float* __restrict__ biasb)
{
  int b = blockIdx.x, side = blockIdx.y;
  const float* Wa = side ? Wa1 : Wa0;
  const float* ba = side ? ba1 : ba0;
  int ids = trip[b * 3 + (side ? 2 : 0)];
  int rid = trip[b * 3 + 1];
  __shared__ float se[H_], re[H_];
  int tid = threadIdx.x;
  if (tid < H_) {
    se[tid] = ent[(size_t)ids * H_ + tid];
    re[tid] = ent[(size_t)rid * H_ + tid];   // reference uses ent_embeds[rids]
  }
  __syncthreads();
  int g = tid;
  if (g < H_) {
    const float* row = Wa + (size_t)g * K3;
    float acc = ba[g];
    for (int h = 0; h < H_; h += 4) {
      float4 ws4 = *(const float4*)&row[H_ + h];
      float4 wr4 = *(const float4*)&row[2 * H_ + h];
      acc += se[h] * ws4.x + se[h+1] * ws4.y + se[h+2] * ws4.z + se[h+3] * ws4.w
           + re[h] * wr4.x + re[h+1] * wr4.y + re[h+2] * wr4.z + re[h+3] * wr4.w;
    }
    biasb[((size_t)side * B_ + b) * H_ + g] = acc;
  }
}

// ---------------------------------------------------------------- gibase[side][b][o] = bih[o] + se.Wih[o,H:2H] + rr.Wih[o,2H:3H]  (bf16 out)
__global__ __launch_bounds__(256) void k_gibase(
    const float* __restrict__ ent, const float* __restrict__ rel, const int* __restrict__ trip,
    const float* __restrict__ Wih0, const float* __restrict__ Wih1,
    const float* __restrict__ bih0, const float* __restrict__ bih1,
    bf16* __restrict__ gibase)
{
  int b = blockIdx.x, side = blockIdx.y;
  const float* Wih = side ? Wih1 : Wih0;
  const float* bih = side ? bih1 : bih0;
  int ids = trip[b * 3 + (side ? 2 : 0)];
  int rid = trip[b * 3 + 1];
  __shared__ float se[H_], rr[H_];
  int tid = threadIdx.x;
  if (tid < H_) {
    se[tid] = ent[(size_t)ids * H_ + tid];
    rr[tid] = rel[(size_t)rid * H_ + tid];
  }
  __syncthreads();
  for (int o = tid; o < K3; o += 256) {
    const float* wr = Wih + (size_t)o * K3;
    float acc = bih[o];
    for (int k = 0; k < H_; k += 4) {
      float4 w2 = *(const float4*)&wr[H_ + k];
      float4 w3 = *(const float4*)&wr[2 * H_ + k];
      acc += se[k] * w2.x + se[k+1] * w2.y + se[k+2] * w2.z + se[k+3] * w2.w
           + rr[k] * w3.x + rr[k+1] * w3.y + rr[k+2] * w3.z + rr[k+3] * w3.w;
    }
    gibase[((size_t)side * B_ + b) * K3 + o] = __float2bfloat16(acc);
  }
}

// ---------------------------------------------------------------- pack GRU weights: Wc[side][n=608][k=448] bf16
// k<200: Wih[n][k] (step part); 224<=k<424: Whh[n][k-224]; else 0. rows>=600: 0.
__global__ __launch_bounds__(256) void k_wc(
    const float* __restrict__ Wih0, const float* __restrict__ Wih1,
    const float* __restrict__ Whh0, const float* __restrict__ Whh1,
    bf16* __restrict__ Wc)
{
  int n = blockIdx.x, side = blockIdx.y;
  const float* Wih = side ? Wih1 : Wih0;
  const float* Whh = side ? Whh1 : Whh0;
  bf16* out = Wc + ((size_t)side * 608 + n) * 448;
  for (int k = threadIdx.x; k < 448; k += 256) {
    float v = 0.f;
    if (n < 600) {
      if (k < 200) v = Wih[(size_t)n * K3 + k];
      else if (k >= 224 && k < 424) v = Whh[(size_t)n * H_ + (k - 224)];
    }
    out[k] = __float2bfloat16(v);
  }
}

// ---------------------------------------------------------------- attention -> step[side][b][t][h] (bf16, masked)
__global__ __launch_bounds__(256) void k_attn(
    const float* __restrict__ ent,
    const int* __restrict__ neigh0, const int* __restrict__ neigh1,
    const int* __restrict__ nlen0, const int* __restrict__ nlen1,
    const int* __restrict__ hlen0, const int* __restrict__ hlen1,
    const float* __restrict__ v0, const float* __restrict__ v1,
    const bf16* __restrict__ ep, const float* __restrict__ biasb,
    bf16* __restrict__ stepb)
{
  int side = blockIdx.y;
  int bt = blockIdx.x;
  int b = bt / T_, t = bt % T_;
  const int* neigh = side ? neigh1 : neigh0;
  const int* nlenA = side ? nlen1 : nlen0;
  const int* hlenA = side ? hlen1 : hlen0;
  const float* v = side ? v1 : v0;
  const bf16* epo = ep + (size_t)side * E_ * H_;
  const float* brow = biasb + ((size_t)side * B_ + b) * H_;

  __shared__ float bsh[H_], vsh[H_], lg[64], wsh[64];
  __shared__ int nb[N_];
  int tid = threadIdx.x;
  if (tid < H_) { bsh[tid] = brow[tid]; vsh[tid] = v[tid]; }
  if (tid < N_) nb[tid] = neigh[((size_t)b * T_ + t) * N_ + tid];
  int nl = nlenA[b * T_ + t];
  int hl = hlenA[b];
  __syncthreads();

  int wave = tid >> 6, lane = tid & 63;
  for (int n = wave; n < N_; n += 4) {
    float acc = 0.f;
    const bf16* er = epo + (size_t)nb[n] * H_;
    for (int g = lane; g < H_; g += 64) acc += tanhf(b2f(er[g]) + bsh[g]) * vsh[g];
    for (int off = 32; off > 0; off >>= 1) acc += __shfl_down(acc, off);
    if (lane == 0) lg[n] = (n < nl) ? acc : -1e30f;
  }
  __syncthreads();
  if (tid < 64) {
    float x = (tid < nl) ? lg[tid] : -1e30f;
    float m = x;
    for (int off = 32; off > 0; off >>= 1) m = fmaxf(m, __shfl_down(m, off));
    m = __shfl(m, 0);
    float e = (tid < nl) ? expf(x - m) : 0.f;
    float s = e;
    for (int off = 32; off > 0; off >>= 1) s += __shfl_down(s, off);
    s = __shfl(s, 0);
    if (tid < N_) wsh[tid] = e / s;
  }
  __syncthreads();
  int h = tid;
  if (h < H_) {
    float st = 0.f;
    for (int n = 0; n < nl; n++) st += wsh[n] * ent[(size_t)nb[n] * H_ + h];
    float msk = (t < hl) ? 1.f : 0.f;
    stepb[(((size_t)side * B_ + b) * T_ + t) * H_ + h] = __float2bfloat16(st * msk);
  }
}

// ---------------------------------------------------------------- MFMA GRU v3
// Block: 16 batch rows, 832 threads = 13 waves; wave w owns gate-col chunk [w*16, w*16+16).
// A-panel Ax[16][456] bf16: cols [0,200)=s_t, [224,424)=h, rest 0.
// Wc rows: [0,200)=r, [200,400)=z, [400,600)=n. gibase/bhh/lens hoisted to registers.
__global__ __launch_bounds__(832) void k_gru3(
    const bf16* __restrict__ stepb, const bf16* __restrict__ gibase,
    const bf16* __restrict__ Wc,
    const float* __restrict__ bhh0, const float* __restrict__ bhh1,
    const int* __restrict__ len0, const int* __restrict__ len1,
    float* __restrict__ hfin)
{
  int side = blockIdx.y;
  int b0 = blockIdx.x * 16;
  const bf16* stp = stepb + (size_t)side * B_ * T_ * H_;
  const bf16* gib = gibase + ((size_t)side * B_ + b0) * K3;
  const bf16* Wcs = Wc + (size_t)side * 608 * 448;
  const float* bhh = side ? bhh1 : bhh0;
  const int* len = side ? len1 : len0;

  __shared__ bf16 Ax[16][456];   // row stride 912B = 228 dw -> +4 banks/row, 2-way max (free)

  int tid = threadIdx.x;
  int wave = tid >> 6, lane = tid & 63;
  int quad = lane >> 4, l15 = lane & 15;

  // zero A panel, then load s_0
  for (int i = tid; i < 16 * 456 / 8; i += 832) ((short8*)&Ax[0][0])[i] = (short8)0;
  __syncthreads();
  for (int i = tid; i < 16 * 25; i += 832) {
    int row = i / 25, seg = i % 25;
    *(short8*)&Ax[row][seg * 8] =
        *(const short8*)&stp[(((size_t)(b0 + row)) * T_ + 0) * H_ + seg * 8];
  }

  // hoist t-invariant per-lane state
  int j0 = wave * 16;
  int j = j0 + l15;
  bool jok = (j < H_);
  float bhr = 0.f, bhz = 0.f, bhn = 0.f;
  float gr[4] = {}, gz[4] = {}, gn[4] = {};
  int lens4[4];
  #pragma unroll
  for (int r = 0; r < 4; r++) lens4[r] = len[b0 + quad * 4 + r];
  if (jok) {
    bhr = bhh[j]; bhz = bhh[H_ + j]; bhn = bhh[2 * H_ + j];
    #pragma unroll
    for (int r = 0; r < 4; r++) {
      const bf16* g = gib + (size_t)(quad * 4 + r) * K3;
      gr[r] = b2f(g[j]); gz[r] = b2f(g[H_ + j]); gn[r] = b2f(g[2 * H_ + j]);
    }
  }
  const bf16* wr = Wcs + (size_t)j * 448;            // rows j0+l15 <= 207
  const bf16* wz = Wcs + (size_t)(200 + j) * 448;
  const bf16* wn = Wcs + (size_t)(400 + j) * 448;    // <= 607 < 608
  __syncthreads();

  for (int t = 0; t < T_; t++) {
    f32x4 ar = {0,0,0,0}, az = {0,0,0,0}, ani = {0,0,0,0}, anh = {0,0,0,0};
    #pragma unroll
    for (int ks = 0; ks < 14; ks++) {
      int kk = ks * 32 + quad * 8;
      short8 a0 = *(const short8*)&Ax[l15][kk];
      short8 br = *(const short8*)&wr[kk];
      short8 bz = *(const short8*)&wz[kk];
      short8 bn = *(const short8*)&wn[kk];
      ar = __builtin_amdgcn_mfma_f32_16x16x32_bf16(a0, br, ar, 0, 0, 0);
      az = __builtin_amdgcn_mfma_f32_16x16x32_bf16(a0, bz, az, 0, 0, 0);
      if (ks < 7) ani = __builtin_amdgcn_mfma_f32_16x16x32_bf16(a0, bn, ani, 0, 0, 0);
      else        anh = __builtin_amdgcn_mfma_f32_16x16x32_bf16(a0, bn, anh, 0, 0, 0);
    }
    // elementwise in registers (C layout: col=l15 -> j, row=quad*4+r)
    bf16 hnew_b[4];
    if (jok) {
      #pragma unroll
      for (int r = 0; r < 4; r++) {
        int row = quad * 4 + r;
        float rz = ar[r] + gr[r] + bhr;
        float zz = az[r] + gz[r] + bhz;
        float inn = ani[r] + gn[r];
        float hn  = anh[r] + bhn;
        float rg = sigm(rz);
        float zg = sigm(zz);
        float ng = tanhf(inn + rg * hn);
        float hold = b2f(Ax[row][224 + j]);
        float hnew = (1.f - zg) * ng + zg * hold;
        hnew_b[r] = __float2bfloat16((t < lens4[r]) ? hnew : hold);
      }
    }
    __syncthreads();   // all MFMA reads + hold reads of Ax done
    if (jok) {
      #pragma unroll
      for (int r = 0; r < 4; r++) Ax[quad * 4 + r][224 + j] = hnew_b[r];
    }
    if (t < T_ - 1) {
      for (int i = tid; i < 16 * 25; i += 832) {
        int row = i / 25, seg = i % 25;
        *(short8*)&Ax[row][seg * 8] =
            *(const short8*)&stp[(((size_t)(b0 + row)) * T_ + (t + 1)) * H_ + seg * 8];
      }
    }
    __syncthreads();
  }
  for (int i = tid; i < 16 * H_; i += 832) {
    int row = i / H_, jj = i % H_;
    hfin[((size_t)side * B_ + b0 + row) * H_ + jj] = b2f(Ax[row][224 + jj]);
  }
}

// ---------------------------------------------------------------- stable descending argsort of hist_len
__global__ __launch_bounds__(512) void k_argsort(
    const int* __restrict__ hlen0, const int* __restrict__ hlen1,
    int* __restrict__ idxbuf, float* __restrict__ dout)
{
  int side = blockIdx.x;                 // 0: s_idx, 1: o_idx
  const int* len = side ? hlen1 : hlen0;
  __shared__ int lens[B_];
  __shared__ int perm[B_];
  int tid = threadIdx.x;
  lens[tid] = len[tid];
  __syncthreads();
  int L = lens[tid];
  int rank = 0;
  for (int j = 0; j < B_; j++) {
    int Lj = lens[j];
    rank += (Lj > L) || (Lj == L && j < tid);
  }
  perm[rank] = tid;
  __syncthreads();
  idxbuf[side * B_ + tid] = perm[tid];
  // output order: (loss, sub_pred, ob_pred, o_idx, s_idx)
  size_t base = 1 + (size_t)2 * B_ * E_ + (side ? 0 : B_);
  dout[base + tid] = (float)perm[tid];
}

// ---------------------------------------------------------------- assemble pred-GEMM input rows (bf16, K padded to 640)
__global__ __launch_bounds__(256) void k_feat(
    const float* __restrict__ ent, const float* __restrict__ rel, const int* __restrict__ trip,
    const int* __restrict__ idxbuf, const float* __restrict__ hfin,
    bf16* __restrict__ xfeat)
{
  int i = blockIdx.x, p = blockIdx.y;    // p=0: sub_pred (o-side), p=1: ob_pred (s-side)
  int bi = idxbuf[(p == 0 ? 1 : 0) * B_ + i];
  int ent_id = (p == 0) ? trip[bi * 3 + 2] : trip[bi * 3 + 0];
  int rid = trip[bi * 3 + 1];
  const float* hsrc = hfin + (size_t)(p == 0 ? 1 : 0) * B_ * H_;
  bf16* x = xfeat + ((size_t)p * B_ + i) * 640;
  int h = threadIdx.x;
  if (h < H_) {
    x[h]          = __float2bfloat16(ent[(size_t)ent_id * H_ + h]);
    x[H_ + h]     = __float2bfloat16(hsrc[(size_t)bi * H_ + h]);
    x[2 * H_ + h] = __float2bfloat16(rel[(size_t)rid * H_ + h]);
  }
  if (h < 40) x[600 + h] = __float2bfloat16(0.f);
}

// ---------------------------------------------------------------- MFMA pred GEMM: C[m][n] = sum_k A[m][k]*B[n][k] + bias[n]
// A bf16 [1024][640] (rows 0..512 side0, 512..1024 side1), B fp32 [10000][600] converted in staging.
// Tile M=128, N=64, BK=64.
__global__ __launch_bounds__(256) void k_gemm2(
    const bf16* __restrict__ Abf,
    const float* __restrict__ B0, const float* __restrict__ B1,
    const float* __restrict__ bias0, const float* __restrict__ bias1,
    float* __restrict__ dout)
{
  int side = blockIdx.z;
  const float* Bm = side ? B1 : B0;
  const float* bias = side ? bias1 : bias0;
  float* C = dout + 1 + (size_t)side * B_ * E_;
  int mBase = blockIdx.x * 128;             // row within side (0..511)
  int m0 = side * B_ + mBase;               // row in Abf
  int n0 = blockIdx.y * 64;

  __shared__ bf16 As[128][72];   // stride 144B = 36 dw -> 2-way banks
  __shared__ bf16 Bs[64][72];

  int tid = threadIdx.x;
  int wave = tid >> 6, lane = tid & 63;
  int quad = lane >> 4, l15 = lane & 15;

  f32x4 acc[8];
  #pragma unroll
  for (int mt = 0; mt < 8; mt++) acc[mt] = (f32x4){0,0,0,0};

  for (int k0 = 0; k0 < 640; k0 += 64) {
    // stage A: 128x64 bf16
    {
      int row = tid >> 1, c0 = (tid & 1) * 32;
      const bf16* src = Abf + (size_t)(m0 + row) * 640 + k0 + c0;
      #pragma unroll
      for (int u = 0; u < 4; u++)
        *(short8*)&As[row][c0 + u * 8] = *(const short8*)&src[u * 8];
    }
    // stage B: 64x64 fp32 -> bf16
    {
      int row = tid >> 2, c0 = (tid & 3) * 16;
      int n = n0 + row;
      if (n < E_ && k0 + c0 + 16 <= K3) {
        const float* src = Bm + (size_t)n * K3 + k0 + c0;
        #pragma unroll
        for (int u = 0; u < 16; u += 4) {
          float4 v = *(const float4*)&src[u];
          Bs[row][c0 + u + 0] = __float2bfloat16(v.x);
          Bs[row][c0 + u + 1] = __float2bfloat16(v.y);
          Bs[row][c0 + u + 2] = __float2bfloat16(v.z);
          Bs[row][c0 + u + 3] = __float2bfloat16(v.w);
        }
      } else {
        #pragma unroll
        for (int u = 0; u < 16; u++) {
          int k = k0 + c0 + u;
          float v = (n < E_ && k < K3) ? Bm[(size_t)n * K3 + k] : 0.f;
          Bs[row][c0 + u] = __float2bfloat16(v);
        }
      }
    }
    __syncthreads();
    #pragma unroll
    for (int ks = 0; ks < 2; ks++) {
      int kk = ks * 32 + quad * 8;
      short8 bfr = *(const short8*)&Bs[wave * 16 + l15][kk];
      #pragma unroll
      for (int mt = 0; mt < 8; mt++) {
        short8 afr = *(const short8*)&As[mt * 16 + l15][kk];
        acc[mt] = __builtin_amdgcn_mfma_f32_16x16x32_bf16(afr, bfr, acc[mt], 0, 0, 0);
      }
    }
    __syncthreads();
  }

  int n = n0 + wave * 16 + l15;
  if (n < E_) {
    float bv = bias[n];
    #pragma unroll
    for (int mt = 0; mt < 8; mt++) {
      #pragma unroll
      for (int r = 0; r < 4; r++) {
        int mrow = mBase + mt * 16 + quad * 4 + r;   // 0..511
        C[(size_t)mrow * E_ + n] = acc[mt][r] + bv;
      }
    }
  }
}

// ---------------------------------------------------------------- CE loss from fp32 pred rows in d_out
__global__ __launch_bounds__(256) void k_loss(
    const float* __restrict__ dout, const int* __restrict__ trip,
    const int* __restrict__ idxbuf, float* __restrict__ lossacc)
{
  int i = blockIdx.x, p = blockIdx.y;
  const float* row = dout + 1 + (size_t)p * B_ * E_ + (size_t)i * E_;
  __shared__ float red[256];
  int tid = threadIdx.x;
  float m = -1e30f;
  for (int e = tid; e < E_; e += 256) m = fmaxf(m, row[e]);
  red[tid] = m; __syncthreads();
  for (int s = 128; s > 0; s >>= 1) { if (tid < s) red[tid] = fmaxf(red[tid], red[tid + s]); __syncthreads(); }
  m = red[0]; __syncthreads();
  float s = 0.f;
  for (int e = tid; e < E_; e += 256) s += expf(row[e] - m);
  red[tid] = s; __syncthreads();
  for (int st = 128; st > 0; st >>= 1) { if (tid < st) red[tid] += red[tid + st]; __syncthreads(); }
  if (tid == 0) {
    int bi = idxbuf[(p == 0 ? 1 : 0) * B_ + i];
    int label = (p == 0) ? trip[bi * 3 + 0] : trip[bi * 3 + 2];
    float lp = row[label] - m - logf(red[0]);
    atomicAdd(lossacc, -lp / (float)B_);
  }
}

__global__ void k_loss_write(const float* __restrict__ lossacc, float* __restrict__ dout){
  if (threadIdx.x == 0) dout[0] = lossacc[0];
}

// ----------------------------------------------------------------
extern "C" void kernel_launch(void* const* d_in, const int* in_sizes, int n_in,
                              void* d_out, int out_size, void* d_ws, size_t ws_size,
                              hipStream_t stream)
{
  const int* trip = (const int*)d_in[0];
  const int* s_ne = (const int*)d_in[1];
  const int* s_nl = (const int*)d_in[2];
  const int* s_hl = (const int*)d_in[3];
  const int* o_ne = (const int*)d_in[4];
  const int* o_nl = (const int*)d_in[5];
  const int* o_hl = (const int*)d_in[6];
  const float* ent = (const float*)d_in[7];
  const float* rel = (const float*)d_in[8];
  const float* aw_s = (const float*)d_in[9];
  const float* ab_s = (const float*)d_in[10];
  const float* v_s  = (const float*)d_in[11];
  const float* aw_o = (const float*)d_in[12];
  const float* ab_o = (const float*)d_in[13];
  const float* v_o  = (const float*)d_in[14];
  const float* sub_wih = (const float*)d_in[15];
  const float* sub_whh = (const float*)d_in[16];
  const float* sub_bih = (const float*)d_in[17];
  const float* sub_bhh = (const float*)d_in[18];
  const float* ob_wih  = (const float*)d_in[19];
  const float* ob_whh  = (const float*)d_in[20];
  const float* ob_bih  = (const float*)d_in[21];
  const float* ob_bhh  = (const float*)d_in[22];
  const float* lin_sub_w = (const float*)d_in[23];
  const float* lin_sub_b = (const float*)d_in[24];
  const float* lin_ob_w  = (const float*)d_in[25];
  const float* lin_ob_b  = (const float*)d_in[26];
  float* dout = (float*)d_out;

  // workspace carve — total ~17.4 MB
  char* w = (char*)d_ws;
  bf16* ep      = (bf16*)w;  w += (size_t)2 * E_ * H_ * 2;        // 8,000,000 B
  bf16* stepb   = (bf16*)w;  w += (size_t)2 * B_ * T_ * H_ * 2;   // 4,096,000 B
  float* biasb  = (float*)w; w += (size_t)2 * B_ * H_ * 4;        //   819,200 B
  bf16* gibase  = (bf16*)w;  w += (size_t)2 * B_ * K3 * 2;        // 1,228,800 B
  float* hfin   = (float*)w; w += (size_t)2 * B_ * H_ * 4;        //   819,200 B
  bf16* xfeat   = (bf16*)w;  w += (size_t)1024 * 640 * 2;         // 1,310,720 B
  bf16* Wc      = (bf16*)w;  w += (size_t)2 * 608 * 448 * 2;      // 1,089,536 B
  float* lossacc= (float*)w; w += 256;
  int* idxbuf   = (int*)w;   w += 4096;

  k_init<<<1, 64, 0, stream>>>(lossacc);
  k_entproj<<<dim3(E_ / 8, 2), 256, 0, stream>>>(ent, aw_s, aw_o, ep);
  k_bias<<<dim3(B_, 2), 256, 0, stream>>>(ent, trip, aw_s, aw_o, ab_s, ab_o, biasb);
  k_gibase<<<dim3(B_, 2), 256, 0, stream>>>(ent, rel, trip, sub_wih, ob_wih,
                                            sub_bih, ob_bih, gibase);
  k_wc<<<dim3(608, 2), 256, 0, stream>>>(sub_wih, ob_wih, sub_whh, ob_whh, Wc);
  k_attn<<<dim3(B_ * T_, 2), 256, 0, stream>>>(ent, s_ne, o_ne, s_nl, o_nl,
                                               s_hl, o_hl, v_s, v_o, ep, biasb, stepb);
  k_gru3<<<dim3(B_ / 16, 2), 832, 0, stream>>>(stepb, gibase, Wc, sub_bhh, ob_bhh,
                                               s_hl, o_hl, hfin);
  k_argsort<<<2, 512, 0, stream>>>(s_hl, o_hl, idxbuf, dout);
  k_feat<<<dim3(B_, 2), 256, 0, stream>>>(ent, rel, trip, idxbuf, hfin, xfeat);
  // pred GEMM: z=0 -> sub_pred (o-side feats, lin_ob), z=1 -> ob_pred (s-side feats, lin_sub)
  k_gemm2<<<dim3(4, (E_ + 63) / 64, 2), 256, 0, stream>>>(
      xfeat, lin_ob_w, lin_sub_w, lin_ob_b, lin_sub_b, dout);
  k_loss<<<dim3(B_, 2), 256, 0, stream>>>(dout, trip, idxbuf, lossacc);
  k_loss_write<<<1, 64, 0, stream>>>(lossacc, dout);
}

// Round 6
// 532.809 us; speedup vs baseline: 2.2651x; 1.4797x over previous
//
#include <hip/hip_runtime.h>
#include <hip/hip_bf16.h>
#include <math.h>

typedef __hip_bfloat16 bf16;
typedef __attribute__((ext_vector_type(8))) short short8;
typedef __attribute__((ext_vector_type(4))) float f32x4;

#define B_ 512
#define T_ 10
#define N_ 50
#define H_ 200
#define E_ 10000
#define R_ 200
#define K3 600   // 3*H

__device__ __forceinline__ float b2f(bf16 x){ return __bfloat162float(x); }
__device__ __forceinline__ float sigm(float x){ return 1.f / (1.f + expf(-x)); }

// ---------------------------------------------------------------- init
__global__ void k_init(float* lossacc){ if(threadIdx.x < 4) lossacc[threadIdx.x] = 0.f; }

// ---------------------------------------------------------------- weight packs (all bf16, zero-padded)
// Wn2[448][256]: rows 0-199 = Wa_s[g][0:200], 200-399 = Wa_o[g-200][0:200], rest 0
__global__ __launch_bounds__(256) void k_pack_wn(
    const float* __restrict__ Wa0, const float* __restrict__ Wa1, bf16* __restrict__ Wn2)
{
  int r = blockIdx.x;
  const float* Wa = (r < 200) ? Wa0 : Wa1;
  int g = (r < 200) ? r : r - 200;
  bf16* out = Wn2 + (size_t)r * 256;
  for (int k = threadIdx.x; k < 256; k += 256) {
    float v = (r < 400 && k < 200) ? Wa[(size_t)g * K3 + k] : 0.f;
    out[k] = __float2bfloat16(v);
  }
}

// dst[side][rpad][448]: rows < nrows = W_side[r][200:600], rest 0
__global__ __launch_bounds__(256) void k_pack_w400(
    const float* __restrict__ W0, const float* __restrict__ W1,
    bf16* __restrict__ dst, int nrows, int rpad)
{
  int r = blockIdx.x, side = blockIdx.y;
  const float* W = side ? W1 : W0;
  bf16* out = dst + ((size_t)side * rpad + r) * 448;
  for (int k = threadIdx.x; k < 448; k += 256) {
    float v = (r < nrows && k < 400) ? W[(size_t)r * K3 + 200 + k] : 0.f;
    out[k] = __float2bfloat16(v);
  }
}

// GRU weights: Wc[side][608][448]: k<200: Wih[n][k]; 224<=k<424: Whh[n][k-224]
__global__ __launch_bounds__(256) void k_wc(
    const float* __restrict__ Wih0, const float* __restrict__ Wih1,
    const float* __restrict__ Whh0, const float* __restrict__ Whh1,
    bf16* __restrict__ Wc)
{
  int n = blockIdx.x, side = blockIdx.y;
  const float* Wih = side ? Wih1 : Wih0;
  const float* Whh = side ? Whh1 : Whh0;
  bf16* out = Wc + ((size_t)side * 608 + n) * 448;
  for (int k = threadIdx.x; k < 448; k += 256) {
    float v = 0.f;
    if (n < 600) {
      if (k < 200) v = Wih[(size_t)n * K3 + k];
      else if (k >= 224 && k < 424) v = Whh[(size_t)n * H_ + (k - 224)];
    }
    out[k] = __float2bfloat16(v);
  }
}

// A-panels for bias/gibase GEMMs: Abias[side*512+b] = [ent[ids]; ent[rid]]; Agi = [ent[ids]; rel[rid]]
__global__ __launch_bounds__(256) void k_afeats(
    const float* __restrict__ ent, const float* __restrict__ rel, const int* __restrict__ trip,
    bf16* __restrict__ Ab, bf16* __restrict__ Ag)
{
  int b = blockIdx.x, side = blockIdx.y;
  int ids = trip[b * 3 + (side ? 2 : 0)];
  int rid = trip[b * 3 + 1];
  size_t ro = ((size_t)side * B_ + b) * 448;
  for (int k = threadIdx.x; k < 448; k += 256) {
    float vb = 0.f, vg = 0.f;
    if (k < 200) { float e = ent[(size_t)ids * H_ + k]; vb = e; vg = e; }
    else if (k < 400) {
      vb = ent[(size_t)rid * H_ + (k - 200)];
      vg = rel[(size_t)rid * H_ + (k - 200)];
    }
    Ab[ro + k] = __float2bfloat16(vb);
    Ag[ro + k] = __float2bfloat16(vg);
  }
}

// ---------------------------------------------------------------- generic MFMA GEMM
// C[m][n] = sum_k A[m][k]*B[n][k] (+ bias[n]); tile M=128, N=64, BK=64.
// AF32: A is fp32 with row length Acols (converted in staging); else bf16 with row length KP.
// B: bf16 [rpad][KP], rows padded so n0+63 always in-bounds. KP multiple of 64.
template<bool OUTBF, bool AF32>
__global__ __launch_bounds__(256) void k_gg(
    const void* __restrict__ Aptr, const bf16* __restrict__ Bptr,
    const float* __restrict__ bias0, const float* __restrict__ bias1,
    void* __restrict__ Cptr,
    int M, int Nout, int KP, int Acols,
    long Astride, long Bstride, long Cstride, int Nstride)
{
  int side = blockIdx.z;
  int m0 = blockIdx.x * 128, n0 = blockIdx.y * 64;

  __shared__ bf16 As[128][72];
  __shared__ bf16 Bs[64][72];

  int tid = threadIdx.x;
  int wave = tid >> 6, lane = tid & 63;
  int quad = lane >> 4, l15 = lane & 15;

  f32x4 acc[8];
  #pragma unroll
  for (int mt = 0; mt < 8; mt++) acc[mt] = (f32x4){0,0,0,0};

  int arow = tid >> 1, ac0 = (tid & 1) * 32;
  int gr = m0 + arow; if (gr > M - 1) gr = M - 1;
  int brow = tid >> 2, bc0 = (tid & 3) * 16;

  for (int k0 = 0; k0 < KP; k0 += 64) {
    if (AF32) {
      const float* src = (const float*)Aptr + (size_t)gr * Acols;
      #pragma unroll
      for (int u = 0; u < 8; u++) {
        int kk = k0 + ac0 + u * 4;
        float4 v;
        if (kk + 4 <= Acols) v = *(const float4*)&src[kk];
        else {
          v.x = (kk + 0 < Acols) ? src[kk + 0] : 0.f;
          v.y = (kk + 1 < Acols) ? src[kk + 1] : 0.f;
          v.z = (kk + 2 < Acols) ? src[kk + 2] : 0.f;
          v.w = (kk + 3 < Acols) ? src[kk + 3] : 0.f;
        }
        As[arow][ac0 + u * 4 + 0] = __float2bfloat16(v.x);
        As[arow][ac0 + u * 4 + 1] = __float2bfloat16(v.y);
        As[arow][ac0 + u * 4 + 2] = __float2bfloat16(v.z);
        As[arow][ac0 + u * 4 + 3] = __float2bfloat16(v.w);
      }
    } else {
      const bf16* src = (const bf16*)Aptr + (size_t)side * Astride + (size_t)gr * KP + k0 + ac0;
      #pragma unroll
      for (int u = 0; u < 4; u++)
        *(short8*)&As[arow][ac0 + u * 8] = *(const short8*)&src[u * 8];
    }
    {
      const bf16* src = Bptr + (size_t)side * Bstride + (size_t)(n0 + brow) * KP + k0 + bc0;
      *(short8*)&Bs[brow][bc0]     = *(const short8*)&src[0];
      *(short8*)&Bs[brow][bc0 + 8] = *(const short8*)&src[8];
    }
    __syncthreads();
    #pragma unroll
    for (int ks = 0; ks < 2; ks++) {
      int kk = ks * 32 + quad * 8;
      short8 bfr = *(const short8*)&Bs[wave * 16 + l15][kk];
      #pragma unroll
      for (int mt = 0; mt < 8; mt++) {
        short8 afr = *(const short8*)&As[mt * 16 + l15][kk];
        acc[mt] = __builtin_amdgcn_mfma_f32_16x16x32_bf16(afr, bfr, acc[mt], 0, 0, 0);
      }
    }
    __syncthreads();
  }

  int n = n0 + wave * 16 + l15;
  if (n < Nout) {
    float bv = bias0 ? (side ? bias1[n] : bias0[n]) : 0.f;
    #pragma unroll
    for (int mt = 0; mt < 8; mt++) {
      #pragma unroll
      for (int r = 0; r < 4; r++) {
        int m = m0 + mt * 16 + quad * 4 + r;
        if (m < M) {
          float val = acc[mt][r] + bv;
          if (OUTBF)
            ((bf16*)Cptr)[(size_t)side * Cstride + (size_t)m * Nstride + n] = __float2bfloat16(val);
          else
            ((float*)Cptr)[(size_t)side * Cstride + (size_t)m * Nstride + n] = val;
        }
      }
    }
  }
}

// ---------------------------------------------------------------- attention -> step[side][b][t][h] (bf16, masked)
// ep2[e][side*200+g] = ent[e].Wn_side[g]
__global__ __launch_bounds__(256) void k_attn(
    const float* __restrict__ ent,
    const int* __restrict__ neigh0, const int* __restrict__ neigh1,
    const int* __restrict__ nlen0, const int* __restrict__ nlen1,
    const int* __restrict__ hlen0, const int* __restrict__ hlen1,
    const float* __restrict__ v0, const float* __restrict__ v1,
    const bf16* __restrict__ ep2, const float* __restrict__ biasb,
    bf16* __restrict__ stepb)
{
  int side = blockIdx.y;
  int bt = blockIdx.x;
  int b = bt / T_, t = bt % T_;
  const int* hlenA = side ? hlen1 : hlen0;
  int hl = hlenA[b];
  if (t >= hl) {     // masked timestep: output is zero, skip all work (uniform branch)
    int h = threadIdx.x;
    if (h < H_) stepb[(((size_t)side * B_ + b) * T_ + t) * H_ + h] = __float2bfloat16(0.f);
    return;
  }
  const int* neigh = side ? neigh1 : neigh0;
  const int* nlenA = side ? nlen1 : nlen0;
  const float* v = side ? v1 : v0;
  const float* brow = biasb + ((size_t)side * B_ + b) * H_;

  __shared__ float bsh[H_], vsh[H_], lg[64], wsh[64];
  __shared__ int nb[N_];
  int tid = threadIdx.x;
  if (tid < H_) { bsh[tid] = brow[tid]; vsh[tid] = v[tid]; }
  if (tid < N_) nb[tid] = neigh[((size_t)b * T_ + t) * N_ + tid];
  int nl = nlenA[b * T_ + t];
  __syncthreads();

  int wave = tid >> 6, lane = tid & 63;
  for (int n = wave; n < nl; n += 4) {
    float acc = 0.f;
    const bf16* er = ep2 + (size_t)nb[n] * 400 + side * 200;
    for (int g = lane; g < H_; g += 64) acc += tanhf(b2f(er[g]) + bsh[g]) * vsh[g];
    for (int off = 32; off > 0; off >>= 1) acc += __shfl_down(acc, off);
    if (lane == 0) lg[n] = acc;
  }
  __syncthreads();
  if (tid < 64) {
    float x = (tid < nl) ? lg[tid] : -1e30f;
    float m = x;
    for (int off = 32; off > 0; off >>= 1) m = fmaxf(m, __shfl_down(m, off));
    m = __shfl(m, 0);
    float e = (tid < nl) ? expf(x - m) : 0.f;
    float s = e;
    for (int off = 32; off > 0; off >>= 1) s += __shfl_down(s, off);
    s = __shfl(s, 0);
    if (tid < N_) wsh[tid] = e / s;
  }
  __syncthreads();
  int h = tid;
  if (h < H_) {
    float st = 0.f;
    for (int n = 0; n < nl; n++) st += wsh[n] * ent[(size_t)nb[n] * H_ + h];
    stepb[(((size_t)side * B_ + b) * T_ + t) * H_ + h] = __float2bfloat16(st);
  }
}

// ---------------------------------------------------------------- MFMA GRU v3 (unchanged from round 5)
__global__ __launch_bounds__(832) void k_gru3(
    const bf16* __restrict__ stepb, const bf16* __restrict__ gibase,
    const bf16* __restrict__ Wc,
    const float* __restrict__ bhh0, const float* __restrict__ bhh1,
    const int* __restrict__ len0, const int* __restrict__ len1,
    float* __restrict__ hfin)
{
  int side = blockIdx.y;
  int b0 = blockIdx.x * 16;
  const bf16* stp = stepb + (size_t)side * B_ * T_ * H_;
  const bf16* gib = gibase + ((size_t)side * B_ + b0) * K3;
  const bf16* Wcs = Wc + (size_t)side * 608 * 448;
  const float* bhh = side ? bhh1 : bhh0;
  const int* len = side ? len1 : len0;

  __shared__ bf16 Ax[16][456];

  int tid = threadIdx.x;
  int wave = tid >> 6, lane = tid & 63;
  int quad = lane >> 4, l15 = lane & 15;

  for (int i = tid; i < 16 * 456 / 8; i += 832) ((short8*)&Ax[0][0])[i] = (short8)0;
  __syncthreads();
  for (int i = tid; i < 16 * 25; i += 832) {
    int row = i / 25, seg = i % 25;
    *(short8*)&Ax[row][seg * 8] =
        *(const short8*)&stp[(((size_t)(b0 + row)) * T_ + 0) * H_ + seg * 8];
  }

  int j0 = wave * 16;
  int j = j0 + l15;
  bool jok = (j < H_);
  float bhr = 0.f, bhz = 0.f, bhn = 0.f;
  float gr[4] = {}, gz[4] = {}, gn[4] = {};
  int lens4[4];
  #pragma unroll
  for (int r = 0; r < 4; r++) lens4[r] = len[b0 + quad * 4 + r];
  if (jok) {
    bhr = bhh[j]; bhz = bhh[H_ + j]; bhn = bhh[2 * H_ + j];
    #pragma unroll
    for (int r = 0; r < 4; r++) {
      const bf16* g = gib + (size_t)(quad * 4 + r) * K3;
      gr[r] = b2f(g[j]); gz[r] = b2f(g[H_ + j]); gn[r] = b2f(g[2 * H_ + j]);
    }
  }
  const bf16* wr = Wcs + (size_t)j * 448;
  const bf16* wz = Wcs + (size_t)(200 + j) * 448;
  const bf16* wn = Wcs + (size_t)(400 + j) * 448;
  __syncthreads();

  for (int t = 0; t < T_; t++) {
    f32x4 ar = {0,0,0,0}, az = {0,0,0,0}, ani = {0,0,0,0}, anh = {0,0,0,0};
    #pragma unroll
    for (int ks = 0; ks < 14; ks++) {
      int kk = ks * 32 + quad * 8;
      short8 a0 = *(const short8*)&Ax[l15][kk];
      short8 br = *(const short8*)&wr[kk];
      short8 bz = *(const short8*)&wz[kk];
      short8 bn = *(const short8*)&wn[kk];
      ar = __builtin_amdgcn_mfma_f32_16x16x32_bf16(a0, br, ar, 0, 0, 0);
      az = __builtin_amdgcn_mfma_f32_16x16x32_bf16(a0, bz, az, 0, 0, 0);
      if (ks < 7) ani = __builtin_amdgcn_mfma_f32_16x16x32_bf16(a0, bn, ani, 0, 0, 0);
      else        anh = __builtin_amdgcn_mfma_f32_16x16x32_bf16(a0, bn, anh, 0, 0, 0);
    }
    bf16 hnew_b[4];
    if (jok) {
      #pragma unroll
      for (int r = 0; r < 4; r++) {
        int row = quad * 4 + r;
        float rz = ar[r] + gr[r] + bhr;
        float zz = az[r] + gz[r] + bhz;
        float inn = ani[r] + gn[r];
        float hn  = anh[r] + bhn;
        float rg = sigm(rz);
        float zg = sigm(zz);
        float ng = tanhf(inn + rg * hn);
        float hold = b2f(Ax[row][224 + j]);
        float hnew = (1.f - zg) * ng + zg * hold;
        hnew_b[r] = __float2bfloat16((t < lens4[r]) ? hnew : hold);
      }
    }
    __syncthreads();
    if (jok) {
      #pragma unroll
      for (int r = 0; r < 4; r++) Ax[quad * 4 + r][224 + j] = hnew_b[r];
    }
    if (t < T_ - 1) {
      for (int i = tid; i < 16 * 25; i += 832) {
        int row = i / 25, seg = i % 25;
        *(short8*)&Ax[row][seg * 8] =
            *(const short8*)&stp[(((size_t)(b0 + row)) * T_ + (t + 1)) * H_ + seg * 8];
      }
    }
    __syncthreads();
  }
  for (int i = tid; i < 16 * H_; i += 832) {
    int row = i / H_, jj = i % H_;
    hfin[((size_t)side * B_ + b0 + row) * H_ + jj] = b2f(Ax[row][224 + jj]);
  }
}

// ---------------------------------------------------------------- stable descending argsort of hist_len
__global__ __launch_bounds__(512) void k_argsort(
    const int* __restrict__ hlen0, const int* __restrict__ hlen1,
    int* __restrict__ idxbuf, float* __restrict__ dout)
{
  int side = blockIdx.x;
  const int* len = side ? hlen1 : hlen0;
  __shared__ int lens[B_];
  __shared__ int perm[B_];
  int tid = threadIdx.x;
  lens[tid] = len[tid];
  __syncthreads();
  int L = lens[tid];
  int rank = 0;
  for (int j = 0; j < B_; j++) {
    int Lj = lens[j];
    rank += (Lj > L) || (Lj == L && j < tid);
  }
  perm[rank] = tid;
  __syncthreads();
  idxbuf[side * B_ + tid] = perm[tid];
  size_t base = 1 + (size_t)2 * B_ * E_ + (side ? 0 : B_);
  dout[base + tid] = (float)perm[tid];
}

// ---------------------------------------------------------------- assemble pred-GEMM input rows (bf16, K padded to 640)
__global__ __launch_bounds__(256) void k_feat(
    const float* __restrict__ ent, const float* __restrict__ rel, const int* __restrict__ trip,
    const int* __restrict__ idxbuf, const float* __restrict__ hfin,
    bf16* __restrict__ xfeat)
{
  int i = blockIdx.x, p = blockIdx.y;
  int bi = idxbuf[(p == 0 ? 1 : 0) * B_ + i];
  int ent_id = (p == 0) ? trip[bi * 3 + 2] : trip[bi * 3 + 0];
  int rid = trip[bi * 3 + 1];
  const float* hsrc = hfin + (size_t)(p == 0 ? 1 : 0) * B_ * H_;
  bf16* x = xfeat + ((size_t)p * B_ + i) * 640;
  int h = threadIdx.x;
  if (h < H_) {
    x[h]          = __float2bfloat16(ent[(size_t)ent_id * H_ + h]);
    x[H_ + h]     = __float2bfloat16(hsrc[(size_t)bi * H_ + h]);
    x[2 * H_ + h] = __float2bfloat16(rel[(size_t)rid * H_ + h]);
  }
  if (h < 40) x[600 + h] = __float2bfloat16(0.f);
}

// ---------------------------------------------------------------- MFMA pred GEMM (B fp32 converted in staging)
__global__ __launch_bounds__(256) void k_gemm2(
    const bf16* __restrict__ Abf,
    const float* __restrict__ B0, const float* __restrict__ B1,
    const float* __restrict__ bias0, const float* __restrict__ bias1,
    float* __restrict__ dout)
{
  int side = blockIdx.z;
  const float* Bm = side ? B1 : B0;
  const float* bias = side ? bias1 : bias0;
  float* C = dout + 1 + (size_t)side * B_ * E_;
  int mBase = blockIdx.x * 128;
  int m0 = side * B_ + mBase;
  int n0 = blockIdx.y * 64;

  __shared__ bf16 As[128][72];
  __shared__ bf16 Bs[64][72];

  int tid = threadIdx.x;
  int wave = tid >> 6, lane = tid & 63;
  int quad = lane >> 4, l15 = lane & 15;

  f32x4 acc[8];
  #pragma unroll
  for (int mt = 0; mt < 8; mt++) acc[mt] = (f32x4){0,0,0,0};

  for (int k0 = 0; k0 < 640; k0 += 64) {
    {
      int row = tid >> 1, c0 = (tid & 1) * 32;
      const bf16* src = Abf + (size_t)(m0 + row) * 640 + k0 + c0;
      #pragma unroll
      for (int u = 0; u < 4; u++)
        *(short8*)&As[row][c0 + u * 8] = *(const short8*)&src[u * 8];
    }
    {
      int row = tid >> 2, c0 = (tid & 3) * 16;
      int n = n0 + row;
      if (n < E_ && k0 + c0 + 16 <= K3) {
        const float* src = Bm + (size_t)n * K3 + k0 + c0;
        #pragma unroll
        for (int u = 0; u < 16; u += 4) {
          float4 v = *(const float4*)&src[u];
          Bs[row][c0 + u + 0] = __float2bfloat16(v.x);
          Bs[row][c0 + u + 1] = __float2bfloat16(v.y);
          Bs[row][c0 + u + 2] = __float2bfloat16(v.z);
          Bs[row][c0 + u + 3] = __float2bfloat16(v.w);
        }
      } else {
        #pragma unroll
        for (int u = 0; u < 16; u++) {
          int k = k0 + c0 + u;
          float v = (n < E_ && k < K3) ? Bm[(size_t)n * K3 + k] : 0.f;
          Bs[row][c0 + u] = __float2bfloat16(v);
        }
      }
    }
    __syncthreads();
    #pragma unroll
    for (int ks = 0; ks < 2; ks++) {
      int kk = ks * 32 + quad * 8;
      short8 bfr = *(const short8*)&Bs[wave * 16 + l15][kk];
      #pragma unroll
      for (int mt = 0; mt < 8; mt++) {
        short8 afr = *(const short8*)&As[mt * 16 + l15][kk];
        acc[mt] = __builtin_amdgcn_mfma_f32_16x16x32_bf16(afr, bfr, acc[mt], 0, 0, 0);
      }
    }
    __syncthreads();
  }

  int n = n0 + wave * 16 + l15;
  if (n < E_) {
    float bv = bias[n];
    #pragma unroll
    for (int mt = 0; mt < 8; mt++) {
      #pragma unroll
      for (int r = 0; r < 4; r++) {
        int mrow = mBase + mt * 16 + quad * 4 + r;
        C[(size_t)mrow * E_ + n] = acc[mt][r] + bv;
      }
    }
  }
}

// ---------------------------------------------------------------- CE loss, online softmax (single pass)
__global__ __launch_bounds__(256) void k_loss(
    const float* __restrict__ dout, const int* __restrict__ trip,
    const int* __restrict__ idxbuf, float* __restrict__ lossacc)
{
  int i = blockIdx.x, p = blockIdx.y;
  const float* row = dout + 1 + (size_t)p * B_ * E_ + (size_t)i * E_;
  int tid = threadIdx.x;
  float m = -1e30f, s = 0.f;
  for (int e = tid; e < E_; e += 256) {
    float x = row[e];
    if (x > m) { s = s * expf(m - x) + 1.f; m = x; }
    else s += expf(x - m);
  }
  __shared__ float ms[256], ss[256];
  ms[tid] = m; ss[tid] = s; __syncthreads();
  for (int st = 128; st > 0; st >>= 1) {
    if (tid < st) {
      float m2 = ms[tid + st], s2 = ss[tid + st];
      float m1 = ms[tid], s1 = ss[tid];
      float mm = fmaxf(m1, m2);
      ss[tid] = s1 * expf(m1 - mm) + s2 * expf(m2 - mm);
      ms[tid] = mm;
    }
    __syncthreads();
  }
  if (tid == 0) {
    int bi = idxbuf[(p == 0 ? 1 : 0) * B_ + i];
    int label = (p == 0) ? trip[bi * 3 + 0] : trip[bi * 3 + 2];
    float lp = row[label] - ms[0] - logf(ss[0]);
    atomicAdd(lossacc, -lp / (float)B_);
  }
}

__global__ void k_loss_write(const float* __restrict__ lossacc, float* __restrict__ dout){
  if (threadIdx.x == 0) dout[0] = lossacc[0];
}

// ----------------------------------------------------------------
extern "C" void kernel_launch(void* const* d_in, const int* in_sizes, int n_in,
                              void* d_out, int out_size, void* d_ws, size_t ws_size,
                              hipStream_t stream)
{
  const int* trip = (const int*)d_in[0];
  const int* s_ne = (const int*)d_in[1];
  const int* s_nl = (const int*)d_in[2];
  const int* s_hl = (const int*)d_in[3];
  const int* o_ne = (const int*)d_in[4];
  const int* o_nl = (const int*)d_in[5];
  const int* o_hl = (const int*)d_in[6];
  const float* ent = (const float*)d_in[7];
  const float* rel = (const float*)d_in[8];
  const float* aw_s = (const float*)d_in[9];
  const float* ab_s = (const float*)d_in[10];
  const float* v_s  = (const float*)d_in[11];
  const float* aw_o = (const float*)d_in[12];
  const float* ab_o = (const float*)d_in[13];
  const float* v_o  = (const float*)d_in[14];
  const float* sub_wih = (const float*)d_in[15];
  const float* sub_whh = (const float*)d_in[16];
  const float* sub_bih = (const float*)d_in[17];
  const float* sub_bhh = (const float*)d_in[18];
  const float* ob_wih  = (const float*)d_in[19];
  const float* ob_whh  = (const float*)d_in[20];
  const float* ob_bih  = (const float*)d_in[21];
  const float* ob_bhh  = (const float*)d_in[22];
  const float* lin_sub_w = (const float*)d_in[23];
  const float* lin_sub_b = (const float*)d_in[24];
  const float* lin_ob_w  = (const float*)d_in[25];
  const float* lin_ob_b  = (const float*)d_in[26];
  float* dout = (float*)d_out;

  // workspace carve — total ~21.0 MB
  char* w = (char*)d_ws;
  bf16* ep2     = (bf16*)w;  w += (size_t)E_ * 400 * 2;           // 8,000,000 B
  bf16* stepb   = (bf16*)w;  w += (size_t)2 * B_ * T_ * H_ * 2;   // 4,096,000 B
  float* biasb  = (float*)w; w += (size_t)2 * B_ * H_ * 4;        //   819,200 B
  bf16* gibase  = (bf16*)w;  w += (size_t)2 * B_ * K3 * 2;        // 1,228,800 B
  float* hfin   = (float*)w; w += (size_t)2 * B_ * H_ * 4;        //   819,200 B
  bf16* xfeat   = (bf16*)w;  w += (size_t)1024 * 640 * 2;         // 1,310,720 B
  bf16* Wc      = (bf16*)w;  w += (size_t)2 * 608 * 448 * 2;      // 1,089,536 B
  bf16* Wn2     = (bf16*)w;  w += (size_t)448 * 256 * 2;          //   229,376 B
  bf16* Wb2     = (bf16*)w;  w += (size_t)2 * 256 * 448 * 2;      //   458,752 B
  bf16* Wg2     = (bf16*)w;  w += (size_t)2 * 640 * 448 * 2;      // 1,146,880 B
  bf16* Abias   = (bf16*)w;  w += (size_t)2 * B_ * 448 * 2;       //   917,504 B
  bf16* Agi     = (bf16*)w;  w += (size_t)2 * B_ * 448 * 2;       //   917,504 B
  float* lossacc= (float*)w; w += 256;
  int* idxbuf   = (int*)w;   w += 4096;

  k_init<<<1, 64, 0, stream>>>(lossacc);
  // packs
  k_pack_wn<<<448, 256, 0, stream>>>(aw_s, aw_o, Wn2);
  k_pack_w400<<<dim3(256, 2), 256, 0, stream>>>(aw_s, aw_o, Wb2, 200, 256);
  k_pack_w400<<<dim3(640, 2), 256, 0, stream>>>(sub_wih, ob_wih, Wg2, 600, 640);
  k_wc<<<dim3(608, 2), 256, 0, stream>>>(sub_wih, ob_wih, sub_whh, ob_whh, Wc);
  k_afeats<<<dim3(B_, 2), 256, 0, stream>>>(ent, rel, trip, Abias, Agi);
  // ep2 = ent @ Wn.T   (M=10000, N=400, K=256pad)
  k_gg<true, true><<<dim3(79, 7, 1), 256, 0, stream>>>(
      (const void*)ent, Wn2, nullptr, nullptr, (void*)ep2,
      E_, 400, 256, 200, 0L, 0L, 0L, 400);
  // biasb = [se;re] @ Wa[:,200:600].T + ba   (M=512/side, N=200, K=448pad)
  k_gg<false, false><<<dim3(4, 4, 2), 256, 0, stream>>>(
      (const void*)Abias, Wb2, ab_s, ab_o, (void*)biasb,
      B_, 200, 448, 448, (long)B_ * 448, 256L * 448, (long)B_ * 200, 200);
  // gibase = [se;rr] @ Wih[:,200:600].T + bih   (M=512/side, N=600, K=448pad)
  k_gg<true, false><<<dim3(4, 10, 2), 256, 0, stream>>>(
      (const void*)Agi, Wg2, sub_bih, ob_bih, (void*)gibase,
      B_, 600, 448, 448, (long)B_ * 448, 640L * 448, (long)B_ * 600, 600);
  // attention
  k_attn<<<dim3(B_ * T_, 2), 256, 0, stream>>>(ent, s_ne, o_ne, s_nl, o_nl,
                                               s_hl, o_hl, v_s, v_o, ep2, biasb, stepb);
  // GRU
  k_gru3<<<dim3(B_ / 16, 2), 832, 0, stream>>>(stepb, gibase, Wc, sub_bhh, ob_bhh,
                                               s_hl, o_hl, hfin);
  k_argsort<<<2, 512, 0, stream>>>(s_hl, o_hl, idxbuf, dout);
  k_feat<<<dim3(B_, 2), 256, 0, stream>>>(ent, rel, trip, idxbuf, hfin, xfeat);
  k_gemm2<<<dim3(4, (E_ + 63) / 64, 2), 256, 0, stream>>>(
      xfeat, lin_ob_w, lin_sub_w, lin_ob_b, lin_sub_b, dout);
  k_loss<<<dim3(B_, 2), 256, 0, stream>>>(dout, trip, idxbuf, lossacc);
  k_loss_write<<<1, 64, 0, stream>>>(lossacc, dout);
}